// Round 14
// baseline (332.966 us; speedup 1.0000x reference)
//
#include <hip/hip_runtime.h>
#include <hip/hip_bf16.h>
#include <math.h>

typedef unsigned long long ull;

// Problem constants
#define BB_ 16          // images
#define PP_ 1000        // proposals per image
#define CC_ 91          // classes incl background
#define FF_ 1024        // feature dim
#define DETS_ 100
#define CAP_ 2048       // candidate capacity per image (measured ~320)
#define CAND_MAX (BB_ * CAP_)
#define SURV_CAP 2048   // NMS-survivor capacity per image
#define CLS_CAP 256     // per-(image,class) candidate capacity
#define BLK_CAND 720    // 8 rows x 90 classes: hard upper bound per block
#define IMG_W 800.0f
#define IMG_H 800.0f
#define OFF_ 802.0f     // max(H,W)+2
#define SCORE_TH 0.05f
#define PRE_TH 0.047f   // prepass cutoff: 3e-3 margin >> 1e-5 fp32 error bound
#define NMS_TH 0.5f
#define MIN_SZ 0.01f
#define BBOX_CLIP_D 4.135166556742356   // log(1000/16)

// ---------------------------------------------------------------------------
// Kernel 0: Wb [1024][364] -> Wbt [91][4][1024] (exact copy, coalesced decode)
// ---------------------------------------------------------------------------
__global__ __launch_bounds__(256) void wb_transpose(
    const float* __restrict__ Wb, float* __restrict__ Wbt)
{
    const int idx = blockIdx.x * 256 + threadIdx.x;
    if (idx >= CC_ * 4 * FF_) return;
    const int c = idx >> 12;
    const int j = (idx >> 10) & 3;
    const int k = idx & 1023;
    if (c < 1) { Wbt[idx] = 0.f; return; }
    Wbt[idx] = Wb[(size_t)k * (CC_ * 4) + 4 * c + j];
}

// ---------------------------------------------------------------------------
// Kernel 1a: fp32 prepass — 32 rows x 91 cols, 500 blocks, 512 threads,
// split-K=2. (unchanged from R13)
// ---------------------------------------------------------------------------
__global__ __launch_bounds__(512) void prepass_rows(
    const float* __restrict__ A, const float* __restrict__ Wc,
    const float* __restrict__ bc,
    int* __restrict__ rowlist, int* __restrict__ nrowsp)
{
    __shared__ union __align__(16) SM {
        struct { float Af[2][16][34]; float Bs[2][16][98]; } t;
        float Ssc[32][97];
    } sm;
    __shared__ float comb[256][12];

    const int tid = threadIdx.x;
    const int kg = tid >> 8;
    const int l = tid & 255;
    const int row0 = blockIdx.x * 32;
    const int kbase = kg * 512;
    const int ty2 = (l >> 4) * 2;
    const int tx6 = (l & 15) * 6;

    const int am = l >> 2;
    const int ak = (l & 3) * 4;
    const int bk = l >> 4;
    const int bn = (l & 15) * 6;

    float acc[2][6];
#pragma unroll
    for (int i = 0; i < 2; ++i)
#pragma unroll
        for (int j = 0; j < 6; ++j) acc[i][j] = 0.f;

    float4 avP = make_float4(0.f, 0.f, 0.f, 0.f);
    if (l < 128)
        avP = *reinterpret_cast<const float4*>(
            A + (size_t)(row0 + am) * FF_ + kbase + ak);
    float bvP[6];
#pragma unroll
    for (int jj = 0; jj < 6; ++jj) {
        const int c = bn + jj;
        bvP[jj] = (c < CC_) ? Wc[(size_t)(kbase + bk) * CC_ + c] : 0.f;
    }

    for (int k0 = 0; k0 < 512; k0 += 16) {
        if (l < 128) {
            sm.t.Af[kg][ak + 0][am] = avP.x;
            sm.t.Af[kg][ak + 1][am] = avP.y;
            sm.t.Af[kg][ak + 2][am] = avP.z;
            sm.t.Af[kg][ak + 3][am] = avP.w;
        }
#pragma unroll
        for (int jj = 0; jj < 6; ++jj) sm.t.Bs[kg][bk][bn + jj] = bvP[jj];

        const int kn = k0 + 16;
        if (kn < 512) {
            if (l < 128)
                avP = *reinterpret_cast<const float4*>(
                    A + (size_t)(row0 + am) * FF_ + kbase + kn + ak);
#pragma unroll
            for (int jj = 0; jj < 6; ++jj) {
                const int c = bn + jj;
                bvP[jj] = (c < CC_) ? Wc[(size_t)(kbase + kn + bk) * CC_ + c] : 0.f;
            }
        }
        __syncthreads();

#pragma unroll
        for (int k = 0; k < 16; ++k) {
            const float2 af = *reinterpret_cast<const float2*>(&sm.t.Af[kg][k][ty2]);
            const float2 b01 = *reinterpret_cast<const float2*>(&sm.t.Bs[kg][k][tx6 + 0]);
            const float2 b23 = *reinterpret_cast<const float2*>(&sm.t.Bs[kg][k][tx6 + 2]);
            const float2 b45 = *reinterpret_cast<const float2*>(&sm.t.Bs[kg][k][tx6 + 4]);
            const float a0 = af.x, a1 = af.y;
            acc[0][0] += a0 * b01.x; acc[0][1] += a0 * b01.y;
            acc[0][2] += a0 * b23.x; acc[0][3] += a0 * b23.y;
            acc[0][4] += a0 * b45.x; acc[0][5] += a0 * b45.y;
            acc[1][0] += a1 * b01.x; acc[1][1] += a1 * b01.y;
            acc[1][2] += a1 * b23.x; acc[1][3] += a1 * b23.y;
            acc[1][4] += a1 * b45.x; acc[1][5] += a1 * b45.y;
        }
        __syncthreads();
    }

    if (kg == 1) {
#pragma unroll
        for (int i = 0; i < 2; ++i)
#pragma unroll
            for (int j = 0; j < 6; ++j) comb[l][i * 6 + j] = acc[i][j];
    }
    __syncthreads();
    if (kg == 0) {
#pragma unroll
        for (int i = 0; i < 2; ++i)
#pragma unroll
            for (int j = 0; j < 6; ++j) {
                const int c = tx6 + j;
                if (c < CC_)
                    sm.Ssc[ty2 + i][c] = acc[i][j] + comb[l][i * 6 + j] + bc[c];
            }
    }
    __syncthreads();

    if (tid < 32) {
        float m_all = sm.Ssc[tid][0];
        float m_fg = -INFINITY;
        for (int c = 1; c < CC_; ++c) {
            const float lv = sm.Ssc[tid][c];
            m_all = fmaxf(m_all, lv);
            m_fg = fmaxf(m_fg, lv);
        }
        float denom = 0.f;
        for (int c = 0; c < CC_; ++c) denom += expf(sm.Ssc[tid][c] - m_all);
        const float maxsc = expf(m_fg - m_all) / denom;
        if (maxsc > PRE_TH) {
            const int pos = atomicAdd(nrowsp, 1);
            rowlist[pos] = row0 + tid;
        }
    }
}

// ---------------------------------------------------------------------------
// Kernel 1b (FUSED): fp64 logits on gathered rows + per-block candidate
// decode. 8 rows/block x 2000 blocks, 512 threads split-K=2, BK=32.
// LDS tiles staged as DOUBLE (exact cvt at staging; per-output products and
// k-order identical to R13 -> bit-identical logits). Decode body verbatim
// from the former decode_cand kernel (same reduction order -> same bits).
// ---------------------------------------------------------------------------
template<bool USE_T>
__global__ __launch_bounds__(512) void logits_fp64_rows(
    const float* __restrict__ A, const float* __restrict__ Wc,
    const float* __restrict__ bc,
    const float* __restrict__ Wb, const float* __restrict__ Wbt,
    const float* __restrict__ bb, const float* __restrict__ props,
    const int* __restrict__ rowlist, const int* __restrict__ nrowsp,
    float* __restrict__ cs, int* __restrict__ clab,
    int* __restrict__ corig, int* __restrict__ cpidx,
    int* __restrict__ cnt,
    float* __restrict__ cx1, float* __restrict__ cy1,
    float* __restrict__ cx2, float* __restrict__ cy2)
{
    const int nr = *nrowsp;
    const int row0 = blockIdx.x * 8;
    if (row0 >= nr) return;

    __shared__ union __align__(16) SM {
        struct { double Ad[2][32][8]; double Bd[2][32][96]; } t;   // 52 KB
        struct { double dcomb[256][3]; float Ssc[8][97];
                 int cp[BLK_CAND]; int cc[BLK_CAND]; int cg[BLK_CAND]; } u;
    } sm;
    __shared__ int ncand;

    const int tid = threadIdx.x;
    const int kg = tid >> 8;
    const int l = tid & 255;
    const int kbase = kg * 512;
    const int r = l >> 5;              // row 0..7
    const int c0 = (l & 31) * 3;       // col base 0..93

    if (tid == 0) ncand = 0;

    // A staging (l < 64): 8 rows x 32 k via float4
    const int aslot = l >> 3;          // 0..7
    const int akq = (l & 7) * 4;       // 0..28
    const float* Arow = nullptr;
    if (l < 64) {
        const int ridx = min(row0 + aslot, nr - 1);
        Arow = A + (size_t)rowlist[ridx] * FF_ + kbase;
    }
    // B staging: 32 k x 96 cols; thread: k-row l>>3, 12 cols at (l&7)*12
    const int bk = l >> 3;             // 0..31
    const int bn = (l & 7) * 12;       // 0..84

    double acc[3] = {0.0, 0.0, 0.0};

    float4 avP = make_float4(0.f, 0.f, 0.f, 0.f);
    if (l < 64) avP = *reinterpret_cast<const float4*>(Arow + akq);
    float bvP[12];
#pragma unroll
    for (int jj = 0; jj < 12; ++jj) {
        const int c = bn + jj;
        bvP[jj] = (c < CC_) ? Wc[(size_t)(kbase + bk) * CC_ + c] : 0.f;
    }

    for (int k0 = 0; k0 < 512; k0 += 32) {
        if (l < 64) {
            sm.t.Ad[kg][akq + 0][aslot] = (double)avP.x;
            sm.t.Ad[kg][akq + 1][aslot] = (double)avP.y;
            sm.t.Ad[kg][akq + 2][aslot] = (double)avP.z;
            sm.t.Ad[kg][akq + 3][aslot] = (double)avP.w;
        }
#pragma unroll
        for (int jj = 0; jj < 12; ++jj)
            sm.t.Bd[kg][bk][bn + jj] = (double)bvP[jj];

        const int kn = k0 + 32;
        if (kn < 512) {
            if (l < 64)
                avP = *reinterpret_cast<const float4*>(Arow + kn + akq);
#pragma unroll
            for (int jj = 0; jj < 12; ++jj) {
                const int c = bn + jj;
                bvP[jj] = (c < CC_) ? Wc[(size_t)(kbase + kn + bk) * CC_ + c] : 0.f;
            }
        }
        __syncthreads();

#pragma unroll
        for (int k = 0; k < 32; ++k) {
            const double a0 = sm.t.Ad[kg][k][r];
            const double b0 = sm.t.Bd[kg][k][c0 + 0];
            const double b1 = sm.t.Bd[kg][k][c0 + 1];
            const double b2 = sm.t.Bd[kg][k][c0 + 2];
            acc[0] += a0 * b0;
            acc[1] += a0 * b1;
            acc[2] += a0 * b2;
        }
        __syncthreads();
    }

    // fixed-order combine lo+hi (tiles dead past barrier above)
    if (kg == 1) {
#pragma unroll
        for (int j = 0; j < 3; ++j) sm.u.dcomb[l][j] = acc[j];
    }
    __syncthreads();
    if (kg == 0) {
#pragma unroll
        for (int j = 0; j < 3; ++j) {
            const int c = c0 + j;
            if (c < CC_) {
                const double v = acc[j] + sm.u.dcomb[l][j];
                sm.u.Ssc[r][c] = __fadd_rn((float)v, bc[c]);
            }
        }
    }
    __syncthreads();

    // wave-parallel softmax: wave w -> row w; lane covers cols lane, lane+64
    {
        const int w = tid >> 6;
        const int lane = tid & 63;
        if (w < 8 && row0 + w < nr) {
            const int p = rowlist[row0 + w];
            const int b = p / PP_;
            const int pi = p - b * PP_;

            const float l1 = sm.u.Ssc[w][lane];
            const float l2 = (lane < CC_ - 64) ? sm.u.Ssc[w][lane + 64] : -INFINITY;
            float m = fmaxf(l1, l2);
#pragma unroll
            for (int off = 32; off > 0; off >>= 1)
                m = fmaxf(m, __shfl_xor(m, off));

            double d = exp((double)l1 - (double)m);
            if (lane < CC_ - 64) d += exp((double)l2 - (double)m);
#pragma unroll
            for (int off = 1; off < 64; off <<= 1)
                d += __shfl_xor(d, off);

#pragma unroll
            for (int q = 0; q < 2; ++q) {
                const int c = lane + q * 64;
                if (c >= 1 && c < CC_) {
                    const double sd = exp((double)sm.u.Ssc[w][c] - (double)m) / d;
                    const float score = (float)sd;
                    if (score > SCORE_TH) {
                        const int pos = atomicAdd(&cnt[b], 1);
                        if (pos < CAP_) {
                            const int g = b * CAP_ + pos;
                            cs[g] = score;
                            clab[g] = c;
                            corig[g] = pi * (CC_ - 1) + (c - 1);
                            cpidx[g] = p;
                            const int slot = atomicAdd(&ncand, 1);
                            if (slot < BLK_CAND) {
                                sm.u.cp[slot] = p;
                                sm.u.cc[slot] = c;
                                sm.u.cg[slot] = g;
                            }
                        }
                    }
                }
            }
        }
    }
    __syncthreads();

    // fused decode: 8 waves iterate over this block's candidates
    {
        const int w = tid >> 6;
        const int lane = tid & 63;
        const int nc = min(ncand, BLK_CAND);
        for (int ci = w; ci < nc; ci += 8) {
            const int p = sm.u.cp[ci];
            const int c = sm.u.cc[ci];
            const int g = sm.u.cg[ci];

            const float* fr = A + (size_t)p * FF_;
            double a0 = 0.0, a1 = 0.0, a2 = 0.0, a3 = 0.0;
            if (USE_T) {
                const float* w0 = Wbt + (size_t)c * 4096;
                for (int k = lane; k < FF_; k += 64) {
                    const double f = (double)fr[k];
                    a0 += f * (double)w0[k];
                    a1 += f * (double)w0[1024 + k];
                    a2 += f * (double)w0[2048 + k];
                    a3 += f * (double)w0[3072 + k];
                }
            } else {
                const float* wb0 = Wb + 4 * c;
                for (int k = lane; k < FF_; k += 64) {
                    const double f = (double)fr[k];
                    const float4 wv = *reinterpret_cast<const float4*>(
                        wb0 + (size_t)k * (CC_ * 4));
                    a0 += f * (double)wv.x; a1 += f * (double)wv.y;
                    a2 += f * (double)wv.z; a3 += f * (double)wv.w;
                }
            }
#pragma unroll
            for (int off = 32; off > 0; off >>= 1) {
                a0 += __shfl_xor(a0, off);
                a1 += __shfl_xor(a1, off);
                a2 += __shfl_xor(a2, off);
                a3 += __shfl_xor(a3, off);
            }

            if (lane == 0) {
                const float dx = __fadd_rn((float)a0, bb[4 * c + 0]);
                const float dy = __fadd_rn((float)a1, bb[4 * c + 1]);
                const float clipf = (float)BBOX_CLIP_D;
                const float dw = fminf(__fadd_rn((float)a2, bb[4 * c + 2]), clipf);
                const float dh = fminf(__fadd_rn((float)a3, bb[4 * c + 3]), clipf);

                const float px1 = props[(size_t)p * 4 + 0];
                const float py1 = props[(size_t)p * 4 + 1];
                const float px2 = props[(size_t)p * 4 + 2];
                const float py2 = props[(size_t)p * 4 + 3];
                const float wq = __fsub_rn(px2, px1);
                const float hq = __fsub_rn(py2, py1);
                const float cxq = __fadd_rn(px1, __fmul_rn(0.5f, wq));
                const float cyq = __fadd_rn(py1, __fmul_rn(0.5f, hq));

                const float pcx = __fadd_rn(__fmul_rn(dx, wq), cxq);
                const float pcy = __fadd_rn(__fmul_rn(dy, hq), cyq);
                const float ew = (float)exp((double)dw);
                const float eh = (float)exp((double)dh);
                const float pw = __fmul_rn(ew, wq);
                const float ph = __fmul_rn(eh, hq);

                const float hw = __fmul_rn(0.5f, pw);
                const float hh = __fmul_rn(0.5f, ph);
                const float bx1 = fminf(fmaxf(__fsub_rn(pcx, hw), 0.f), IMG_W);
                const float by1 = fminf(fmaxf(__fsub_rn(pcy, hh), 0.f), IMG_H);
                const float bx2 = fminf(fmaxf(__fadd_rn(pcx, hw), 0.f), IMG_W);
                const float by2 = fminf(fmaxf(__fadd_rn(pcy, hh), 0.f), IMG_H);

                cx1[g] = bx1; cy1[g] = by1; cx2[g] = bx2; cy2[g] = by2;
                if (!(__fsub_rn(bx2, bx1) >= MIN_SZ && __fsub_rn(by2, by1) >= MIN_SZ)) {
                    cs[g] = -INFINITY;
                }
            }
        }
    }
}

// ---------------------------------------------------------------------------
// Kernel 3: per-(image,class) greedy NMS — one wave per (b,c) pair.
// (unchanged — bit-exact)
// ---------------------------------------------------------------------------
__global__ __launch_bounds__(64) void nms_class(
    const float* __restrict__ c_x1, const float* __restrict__ c_y1,
    const float* __restrict__ c_x2, const float* __restrict__ c_y2,
    const float* __restrict__ c_s, const int* __restrict__ c_lab,
    const int* __restrict__ c_orig, const int* __restrict__ cnt,
    ull* __restrict__ skey, float* __restrict__ sx1v, float* __restrict__ sy1v,
    float* __restrict__ sx2v, float* __restrict__ sy2v,
    int* __restrict__ slabv, int* __restrict__ scnt)
{
    const int blk = blockIdx.x;
    const int b = blk / (CC_ - 1);
    const int c = 1 + (blk - b * (CC_ - 1));
    const int lane = threadIdx.x;

    __shared__ ull kk[CLS_CAP];
    __shared__ float x1s[CLS_CAP], y1s[CLS_CAP], x2s[CLS_CAP], y2s[CLS_CAP];

    const int n = min(cnt[b], CAP_);

    int mcnt = 0;
    for (int i0 = 0; i0 < n; i0 += 64) {
        const int i = i0 + lane;
        bool take = false;
        float s = 0.f; int so = 0; int g = 0;
        if (i < n) {
            g = b * CAP_ + i;
            if (c_lab[g] == c) {
                s = c_s[g];
                if (s > 0.f) { take = true; so = c_orig[g]; }
            }
        }
        const ull bal = __ballot(take);
        if (take) {
            const int pos = mcnt + __popcll(bal & ((1ull << lane) - 1ull));
            if (pos < CLS_CAP) {
                kk[pos] = ((ull)__float_as_uint(s) << 32) |
                          (unsigned int)(0x7FFFFFFF - so);
                x1s[pos] = c_x1[g]; y1s[pos] = c_y1[g];
                x2s[pos] = c_x2[g]; y2s[pos] = c_y2[g];
            }
        }
        mcnt += (int)__popcll(bal);
    }
    mcnt = min(mcnt, CLS_CAP);
    if (mcnt == 0) return;
    __syncthreads();

    while (true) {
        ull best = 0ull;
        for (int i = lane; i < mcnt; i += 64) best = (kk[i] > best) ? kk[i] : best;
#pragma unroll
        for (int off = 32; off > 0; off >>= 1) {
            const ull o = __shfl_xor(best, off);
            best = (o > best) ? o : best;
        }
        if (best == 0ull) break;

        int wsl = -1;
        for (int i = lane; i < mcnt; i += 64) if (kk[i] == best) wsl = i;
        const ull bal = __ballot(wsl >= 0);
        const int wlane = (int)__ffsll((long long)bal) - 1;
        wsl = __shfl(wsl, wlane);

        const float wx1 = x1s[wsl], wy1 = y1s[wsl];
        const float wx2 = x2s[wsl], wy2 = y2s[wsl];

        if (lane == 0) {
            const int sp = atomicAdd(&scnt[b], 1);
            if (sp < SURV_CAP) {
                const int sg = b * SURV_CAP + sp;
                skey[sg] = best;
                sx1v[sg] = wx1; sy1v[sg] = wy1;
                sx2v[sg] = wx2; sy2v[sg] = wy2;
                slabv[sg] = c;
            }
        }

        const float off = __fmul_rn((float)c, OFF_);
        const float ax1 = __fadd_rn(wx1, off), ay1 = __fadd_rn(wy1, off);
        const float ax2 = __fadd_rn(wx2, off), ay2 = __fadd_rn(wy2, off);
        const float a1 = __fmul_rn(__fsub_rn(ax2, ax1), __fsub_rn(ay2, ay1));
        for (int i = lane; i < mcnt; i += 64) {
            if (kk[i] == 0ull) continue;
            const float bx1 = __fadd_rn(x1s[i], off), by1 = __fadd_rn(y1s[i], off);
            const float bx2 = __fadd_rn(x2s[i], off), by2 = __fadd_rn(y2s[i], off);
            const float ix1 = fmaxf(ax1, bx1), iy1 = fmaxf(ay1, by1);
            const float ix2 = fminf(ax2, bx2), iy2 = fminf(ay2, by2);
            const float inter = __fmul_rn(fmaxf(__fsub_rn(ix2, ix1), 0.f),
                                          fmaxf(__fsub_rn(iy2, iy1), 0.f));
            const float a2 = __fmul_rn(__fsub_rn(bx2, bx1), __fsub_rn(by2, by1));
            const float den = __fadd_rn(__fsub_rn(__fadd_rn(a1, a2), inter), 1e-9f);
            const float iou = __fdiv_rn(inter, den);
            if (iou > NMS_TH) kk[i] = 0ull;
        }
        __syncthreads();
    }
}

// ---------------------------------------------------------------------------
// Kernel 4: per-image merge — bitonic sort survivors by key (desc), emit
// top-100 in order. (unchanged — bit-exact)
// ---------------------------------------------------------------------------
__global__ __launch_bounds__(256) void nms_merge(
    const ull* __restrict__ skey, const float* __restrict__ sx1v,
    const float* __restrict__ sy1v, const float* __restrict__ sx2v,
    const float* __restrict__ sy2v, const int* __restrict__ slabv,
    const int* __restrict__ scnt, float* __restrict__ out)
{
    const int b = blockIdx.x;
    const int t = threadIdx.x;

    __shared__ ull k_[SURV_CAP];
    __shared__ int id_[SURV_CAP];

    const int m = min(scnt[b], SURV_CAP);
    int N2 = 128;
    while (N2 < m) N2 <<= 1;

    for (int i = t; i < N2; i += 256) {
        k_[i] = (i < m) ? skey[b * SURV_CAP + i] : 0ull;
        id_[i] = i;
    }
    __syncthreads();

    for (int ksz = 2; ksz <= N2; ksz <<= 1) {
        for (int j = ksz >> 1; j > 0; j >>= 1) {
            for (int i = t; i < N2; i += 256) {
                const int ixj = i ^ j;
                if (ixj > i) {
                    const ull a = k_[i], cc = k_[ixj];
                    const bool desc = ((i & ksz) == 0);
                    if (desc ? (a < cc) : (a > cc)) {
                        k_[i] = cc; k_[ixj] = a;
                        const int tmp = id_[i]; id_[i] = id_[ixj]; id_[ixj] = tmp;
                    }
                }
            }
            __syncthreads();
        }
    }

    const int boxes_base = 0;
    const int scores_base = BB_ * DETS_ * 4;
    const int labels_base = BB_ * DETS_ * 5;

    for (int r = t; r < DETS_; r += 256) {
        const ull key = (r < N2) ? k_[r] : 0ull;
        float* bo = out + boxes_base + (size_t)(b * DETS_ + r) * 4;
        if (key != 0ull) {
            const int sg = b * SURV_CAP + id_[r];
            bo[0] = sx1v[sg]; bo[1] = sy1v[sg];
            bo[2] = sx2v[sg]; bo[3] = sy2v[sg];
            out[scores_base + b * DETS_ + r] = __uint_as_float((unsigned)(key >> 32));
            out[labels_base + b * DETS_ + r] = (float)slabv[sg];
        } else {
            bo[0] = 0.f; bo[1] = 0.f; bo[2] = 0.f; bo[3] = 0.f;
            out[scores_base + b * DETS_ + r] = 0.f;
            out[labels_base + b * DETS_ + r] = 0.f;
        }
    }
}

// ---------------------------------------------------------------------------
extern "C" void kernel_launch(void* const* d_in, const int* in_sizes, int n_in,
                              void* d_out, int out_size, void* d_ws, size_t ws_size,
                              hipStream_t stream)
{
    const float* feat  = (const float*)d_in[0];
    const float* Wc    = (const float*)d_in[1];
    const float* bc    = (const float*)d_in[2];
    const float* Wb    = (const float*)d_in[3];
    const float* bb    = (const float*)d_in[4];
    const float* props = (const float*)d_in[5];
    for (int i = 0; i < n_in; ++i) {
        const float* q = (const float*)d_in[i];
        switch (in_sizes[i]) {
            case 16384000: feat  = q; break;  // [16000,1024]
            case 93184:    Wc    = q; break;  // [1024,91]
            case 91:       bc    = q; break;
            case 372736:   Wb    = q; break;  // [1024,364]
            case 364:      bb    = q; break;
            case 64000:    props = q; break;  // [16,1000,4]
        }
    }
    float* out = (float*)d_out;

    char* ws = (char*)d_ws;
    int*   cnt    = (int*)ws;            // 16 ints
    int*   scnt   = (int*)(ws + 64);     // 16 ints
    int*   nrowsp = (int*)(ws + 128);    // 1 int
    float* cs    = (float*)(ws + 256);
    int*   clab  = (int*)(cs + CAND_MAX);
    int*   corig = clab + CAND_MAX;
    int*   cpidx = corig + CAND_MAX;
    float* cx1   = (float*)(cpidx + CAND_MAX);
    float* cy1   = cx1 + CAND_MAX;
    float* cx2   = cy1 + CAND_MAX;
    float* cy2   = cx2 + CAND_MAX;
    ull*   skey  = (ull*)(cy2 + CAND_MAX);
    float* sx1v  = (float*)(skey + (size_t)BB_ * SURV_CAP);
    float* sy1v  = sx1v + (size_t)BB_ * SURV_CAP;
    float* sx2v  = sy1v + (size_t)BB_ * SURV_CAP;
    float* sy2v  = sx2v + (size_t)BB_ * SURV_CAP;
    int*   slabv = (int*)(sy2v + (size_t)BB_ * SURV_CAP);
    int*   rowlist = slabv + (size_t)BB_ * SURV_CAP;   // 16000 ints
    float* Wbt   = (float*)(rowlist + 16384);          // 91*4*1024 floats

    const size_t need = ((char*)(Wbt + CC_ * 4 * FF_)) - ws;
    const bool useT = (ws_size >= need);

    hipMemsetAsync(ws, 0, 256, stream);   // zero cnt + scnt + nrows

    if (useT)
        wb_transpose<<<(CC_ * 4 * FF_ + 255) / 256, 256, 0, stream>>>(Wb, Wbt);

    prepass_rows<<<BB_ * PP_ / 32, 512, 0, stream>>>(feat, Wc, bc,
        rowlist, nrowsp);

    if (useT)
        logits_fp64_rows<true><<<BB_ * PP_ / 8, 512, 0, stream>>>(
            feat, Wc, bc, Wb, Wbt, bb, props, rowlist, nrowsp,
            cs, clab, corig, cpidx, cnt, cx1, cy1, cx2, cy2);
    else
        logits_fp64_rows<false><<<BB_ * PP_ / 8, 512, 0, stream>>>(
            feat, Wc, bc, Wb, Wbt, bb, props, rowlist, nrowsp,
            cs, clab, corig, cpidx, cnt, cx1, cy1, cx2, cy2);

    nms_class<<<BB_ * (CC_ - 1), 64, 0, stream>>>(
        cx1, cy1, cx2, cy2, cs, clab, corig, cnt,
        skey, sx1v, sy1v, sx2v, sy2v, slabv, scnt);

    nms_merge<<<BB_, 256, 0, stream>>>(
        skey, sx1v, sy1v, sx2v, sy2v, slabv, scnt, out);
}

// Round 15
// 288.416 us; speedup vs baseline: 1.1545x; 1.1545x over previous
//
#include <hip/hip_runtime.h>
#include <hip/hip_bf16.h>
#include <math.h>

typedef unsigned long long ull;

// Problem constants
#define BB_ 16          // images
#define PP_ 1000        // proposals per image
#define CC_ 91          // classes incl background
#define FF_ 1024        // feature dim
#define DETS_ 100
#define CAP_ 2048       // candidate capacity per image (measured ~320)
#define CAND_MAX (BB_ * CAP_)
#define SURV_CAP 2048   // NMS-survivor capacity per image
#define CLS_CAP 256     // per-(image,class) candidate capacity
#define BLK_CAND 720    // 8 rows x 90 classes: hard upper bound per block
#define IMG_W 800.0f
#define IMG_H 800.0f
#define OFF_ 802.0f     // max(H,W)+2
#define SCORE_TH 0.05f
#define PRE_TH 0.047f   // prepass cutoff: 3e-3 margin >> 1e-5 fp32 error bound
#define NMS_TH 0.5f
#define MIN_SZ 0.01f
#define BBOX_CLIP_D 4.135166556742356   // log(1000/16)

// ---------------------------------------------------------------------------
// Kernel 0: Wb [1024][364] -> Wbt [91][4][1024] (exact copy, coalesced decode)
// ---------------------------------------------------------------------------
__global__ __launch_bounds__(256) void wb_transpose(
    const float* __restrict__ Wb, float* __restrict__ Wbt)
{
    const int idx = blockIdx.x * 256 + threadIdx.x;
    if (idx >= CC_ * 4 * FF_) return;
    const int c = idx >> 12;
    const int j = (idx >> 10) & 3;
    const int k = idx & 1023;
    if (c < 1) { Wbt[idx] = 0.f; return; }
    Wbt[idx] = Wb[(size_t)k * (CC_ * 4) + 4 * c + j];
}

// ---------------------------------------------------------------------------
// Kernel 1a: fp32 prepass — 32 rows x 91 cols, 500 blocks, 512 threads,
// split-K=2. (unchanged from R13)
// ---------------------------------------------------------------------------
__global__ __launch_bounds__(512) void prepass_rows(
    const float* __restrict__ A, const float* __restrict__ Wc,
    const float* __restrict__ bc,
    int* __restrict__ rowlist, int* __restrict__ nrowsp)
{
    __shared__ union __align__(16) SM {
        struct { float Af[2][16][34]; float Bs[2][16][98]; } t;
        float Ssc[32][97];
    } sm;
    __shared__ float comb[256][12];

    const int tid = threadIdx.x;
    const int kg = tid >> 8;
    const int l = tid & 255;
    const int row0 = blockIdx.x * 32;
    const int kbase = kg * 512;
    const int ty2 = (l >> 4) * 2;
    const int tx6 = (l & 15) * 6;

    const int am = l >> 2;
    const int ak = (l & 3) * 4;
    const int bk = l >> 4;
    const int bn = (l & 15) * 6;

    float acc[2][6];
#pragma unroll
    for (int i = 0; i < 2; ++i)
#pragma unroll
        for (int j = 0; j < 6; ++j) acc[i][j] = 0.f;

    float4 avP = make_float4(0.f, 0.f, 0.f, 0.f);
    if (l < 128)
        avP = *reinterpret_cast<const float4*>(
            A + (size_t)(row0 + am) * FF_ + kbase + ak);
    float bvP[6];
#pragma unroll
    for (int jj = 0; jj < 6; ++jj) {
        const int c = bn + jj;
        bvP[jj] = (c < CC_) ? Wc[(size_t)(kbase + bk) * CC_ + c] : 0.f;
    }

    for (int k0 = 0; k0 < 512; k0 += 16) {
        if (l < 128) {
            sm.t.Af[kg][ak + 0][am] = avP.x;
            sm.t.Af[kg][ak + 1][am] = avP.y;
            sm.t.Af[kg][ak + 2][am] = avP.z;
            sm.t.Af[kg][ak + 3][am] = avP.w;
        }
#pragma unroll
        for (int jj = 0; jj < 6; ++jj) sm.t.Bs[kg][bk][bn + jj] = bvP[jj];

        const int kn = k0 + 16;
        if (kn < 512) {
            if (l < 128)
                avP = *reinterpret_cast<const float4*>(
                    A + (size_t)(row0 + am) * FF_ + kbase + kn + ak);
#pragma unroll
            for (int jj = 0; jj < 6; ++jj) {
                const int c = bn + jj;
                bvP[jj] = (c < CC_) ? Wc[(size_t)(kbase + kn + bk) * CC_ + c] : 0.f;
            }
        }
        __syncthreads();

#pragma unroll
        for (int k = 0; k < 16; ++k) {
            const float2 af = *reinterpret_cast<const float2*>(&sm.t.Af[kg][k][ty2]);
            const float2 b01 = *reinterpret_cast<const float2*>(&sm.t.Bs[kg][k][tx6 + 0]);
            const float2 b23 = *reinterpret_cast<const float2*>(&sm.t.Bs[kg][k][tx6 + 2]);
            const float2 b45 = *reinterpret_cast<const float2*>(&sm.t.Bs[kg][k][tx6 + 4]);
            const float a0 = af.x, a1 = af.y;
            acc[0][0] += a0 * b01.x; acc[0][1] += a0 * b01.y;
            acc[0][2] += a0 * b23.x; acc[0][3] += a0 * b23.y;
            acc[0][4] += a0 * b45.x; acc[0][5] += a0 * b45.y;
            acc[1][0] += a1 * b01.x; acc[1][1] += a1 * b01.y;
            acc[1][2] += a1 * b23.x; acc[1][3] += a1 * b23.y;
            acc[1][4] += a1 * b45.x; acc[1][5] += a1 * b45.y;
        }
        __syncthreads();
    }

    if (kg == 1) {
#pragma unroll
        for (int i = 0; i < 2; ++i)
#pragma unroll
            for (int j = 0; j < 6; ++j) comb[l][i * 6 + j] = acc[i][j];
    }
    __syncthreads();
    if (kg == 0) {
#pragma unroll
        for (int i = 0; i < 2; ++i)
#pragma unroll
            for (int j = 0; j < 6; ++j) {
                const int c = tx6 + j;
                if (c < CC_)
                    sm.Ssc[ty2 + i][c] = acc[i][j] + comb[l][i * 6 + j] + bc[c];
            }
    }
    __syncthreads();

    if (tid < 32) {
        float m_all = sm.Ssc[tid][0];
        float m_fg = -INFINITY;
        for (int c = 1; c < CC_; ++c) {
            const float lv = sm.Ssc[tid][c];
            m_all = fmaxf(m_all, lv);
            m_fg = fmaxf(m_fg, lv);
        }
        float denom = 0.f;
        for (int c = 0; c < CC_; ++c) denom += expf(sm.Ssc[tid][c] - m_all);
        const float maxsc = expf(m_fg - m_all) / denom;
        if (maxsc > PRE_TH) {
            const int pos = atomicAdd(nrowsp, 1);
            rowlist[pos] = row0 + tid;
        }
    }
}

// ---------------------------------------------------------------------------
// Kernel 1b (FUSED): R13's fp64 logits kernel VERBATIM (fp32 LDS tiles,
// BK=16, split-K=2, 8 rows/block) + fused per-block candidate decode.
// Candidate records overlay the dead GEMM tiles via union (LDS unchanged).
// ---------------------------------------------------------------------------
template<bool USE_T>
__global__ __launch_bounds__(512) void logits_fp64_rows(
    const float* __restrict__ A, const float* __restrict__ Wc,
    const float* __restrict__ bc,
    const float* __restrict__ Wb, const float* __restrict__ Wbt,
    const float* __restrict__ bb, const float* __restrict__ props,
    const int* __restrict__ rowlist, const int* __restrict__ nrowsp,
    float* __restrict__ cs, int* __restrict__ clab,
    int* __restrict__ corig, int* __restrict__ cpidx,
    int* __restrict__ cnt,
    float* __restrict__ cx1, float* __restrict__ cy1,
    float* __restrict__ cx2, float* __restrict__ cy2)
{
    const int nr = *nrowsp;
    const int row0 = blockIdx.x * 8;
    if (row0 >= nr) return;

    __shared__ union __align__(16) SM {
        struct { float Af[2][16][12]; float Bs[2][16][98]; } t;   // 14 KB
        struct { int cp[BLK_CAND]; int cc[BLK_CAND]; int cg[BLK_CAND]; } d;
    } sm;
    __shared__ __align__(16) double dcomb[256][3];  // 6 KB
    __shared__ float Ssc[8][97];                    // 3.1 KB
    __shared__ int ncand;

    const int tid = threadIdx.x;
    const int kg = tid >> 8;
    const int l = tid & 255;
    const int kbase = kg * 512;
    const int r = l >> 5;              // row 0..7
    const int c0 = (l & 31) * 3;       // col base 0..93

    if (tid == 0) ncand = 0;

    // A staging (l < 32): 8 rows x 16 k via float4
    const int aslot = l >> 2;          // 0..7
    const int akq = (l & 3) * 4;
    const float* Arow = nullptr;
    if (l < 32) {
        const int ridx = min(row0 + aslot, nr - 1);
        Arow = A + (size_t)rowlist[ridx] * FF_ + kbase;
    }
    // B staging: 16 k x 96 cols, 6 scalars
    const int bk = l >> 4;
    const int bn = (l & 15) * 6;

    double acc[3] = {0.0, 0.0, 0.0};

    float4 avP = make_float4(0.f, 0.f, 0.f, 0.f);
    if (l < 32) avP = *reinterpret_cast<const float4*>(Arow + akq);
    float bvP[6];
#pragma unroll
    for (int jj = 0; jj < 6; ++jj) {
        const int c = bn + jj;
        bvP[jj] = (c < CC_) ? Wc[(size_t)(kbase + bk) * CC_ + c] : 0.f;
    }

    for (int k0 = 0; k0 < 512; k0 += 16) {
        if (l < 32) {
            sm.t.Af[kg][akq + 0][aslot] = avP.x;
            sm.t.Af[kg][akq + 1][aslot] = avP.y;
            sm.t.Af[kg][akq + 2][aslot] = avP.z;
            sm.t.Af[kg][akq + 3][aslot] = avP.w;
        }
#pragma unroll
        for (int jj = 0; jj < 6; ++jj) sm.t.Bs[kg][bk][bn + jj] = bvP[jj];

        const int kn = k0 + 16;
        if (kn < 512) {
            if (l < 32)
                avP = *reinterpret_cast<const float4*>(Arow + kn + akq);
#pragma unroll
            for (int jj = 0; jj < 6; ++jj) {
                const int c = bn + jj;
                bvP[jj] = (c < CC_) ? Wc[(size_t)(kbase + kn + bk) * CC_ + c] : 0.f;
            }
        }
        __syncthreads();

#pragma unroll
        for (int k = 0; k < 16; ++k) {
            const double a0 = (double)sm.t.Af[kg][k][r];
            const double b0 = (double)sm.t.Bs[kg][k][c0 + 0];
            const double b1 = (double)sm.t.Bs[kg][k][c0 + 1];
            const double b2 = (double)sm.t.Bs[kg][k][c0 + 2];
            acc[0] += a0 * b0;
            acc[1] += a0 * b1;
            acc[2] += a0 * b2;
        }
        __syncthreads();
    }

    // fixed-order combine lo+hi
    if (kg == 1) {
#pragma unroll
        for (int j = 0; j < 3; ++j) dcomb[l][j] = acc[j];
    }
    __syncthreads();
    if (kg == 0) {
#pragma unroll
        for (int j = 0; j < 3; ++j) {
            const int c = c0 + j;
            if (c < CC_) {
                const double v = acc[j] + dcomb[l][j];
                Ssc[r][c] = __fadd_rn((float)v, bc[c]);
            }
        }
    }
    __syncthreads();   // Ssc ready; GEMM tiles dead -> sm.d usable

    // wave-parallel softmax: wave w -> row w; lane covers cols lane, lane+64
    {
        const int w = tid >> 6;
        const int lane = tid & 63;
        if (w < 8 && row0 + w < nr) {
            const int p = rowlist[row0 + w];
            const int b = p / PP_;
            const int pi = p - b * PP_;

            const float l1 = Ssc[w][lane];
            const float l2 = (lane < CC_ - 64) ? Ssc[w][lane + 64] : -INFINITY;
            float m = fmaxf(l1, l2);
#pragma unroll
            for (int off = 32; off > 0; off >>= 1)
                m = fmaxf(m, __shfl_xor(m, off));

            double d = exp((double)l1 - (double)m);
            if (lane < CC_ - 64) d += exp((double)l2 - (double)m);
#pragma unroll
            for (int off = 1; off < 64; off <<= 1)
                d += __shfl_xor(d, off);

#pragma unroll
            for (int q = 0; q < 2; ++q) {
                const int c = lane + q * 64;
                if (c >= 1 && c < CC_) {
                    const double sd = exp((double)Ssc[w][c] - (double)m) / d;
                    const float score = (float)sd;
                    if (score > SCORE_TH) {
                        const int pos = atomicAdd(&cnt[b], 1);
                        if (pos < CAP_) {
                            const int g = b * CAP_ + pos;
                            cs[g] = score;
                            clab[g] = c;
                            corig[g] = pi * (CC_ - 1) + (c - 1);
                            cpidx[g] = p;
                            const int slot = atomicAdd(&ncand, 1);
                            if (slot < BLK_CAND) {
                                sm.d.cp[slot] = p;
                                sm.d.cc[slot] = c;
                                sm.d.cg[slot] = g;
                            }
                        }
                    }
                }
            }
        }
    }
    __syncthreads();

    // fused decode: 8 waves iterate over this block's candidates
    {
        const int w = tid >> 6;
        const int lane = tid & 63;
        const int nc = min(ncand, BLK_CAND);
        for (int ci = w; ci < nc; ci += 8) {
            const int p = sm.d.cp[ci];
            const int c = sm.d.cc[ci];
            const int g = sm.d.cg[ci];

            const float* fr = A + (size_t)p * FF_;
            double a0 = 0.0, a1 = 0.0, a2 = 0.0, a3 = 0.0;
            if (USE_T) {
                const float* w0 = Wbt + (size_t)c * 4096;
                for (int k = lane; k < FF_; k += 64) {
                    const double f = (double)fr[k];
                    a0 += f * (double)w0[k];
                    a1 += f * (double)w0[1024 + k];
                    a2 += f * (double)w0[2048 + k];
                    a3 += f * (double)w0[3072 + k];
                }
            } else {
                const float* wb0 = Wb + 4 * c;
                for (int k = lane; k < FF_; k += 64) {
                    const double f = (double)fr[k];
                    const float4 wv = *reinterpret_cast<const float4*>(
                        wb0 + (size_t)k * (CC_ * 4));
                    a0 += f * (double)wv.x; a1 += f * (double)wv.y;
                    a2 += f * (double)wv.z; a3 += f * (double)wv.w;
                }
            }
#pragma unroll
            for (int off = 32; off > 0; off >>= 1) {
                a0 += __shfl_xor(a0, off);
                a1 += __shfl_xor(a1, off);
                a2 += __shfl_xor(a2, off);
                a3 += __shfl_xor(a3, off);
            }

            if (lane == 0) {
                const float dx = __fadd_rn((float)a0, bb[4 * c + 0]);
                const float dy = __fadd_rn((float)a1, bb[4 * c + 1]);
                const float clipf = (float)BBOX_CLIP_D;
                const float dw = fminf(__fadd_rn((float)a2, bb[4 * c + 2]), clipf);
                const float dh = fminf(__fadd_rn((float)a3, bb[4 * c + 3]), clipf);

                const float px1 = props[(size_t)p * 4 + 0];
                const float py1 = props[(size_t)p * 4 + 1];
                const float px2 = props[(size_t)p * 4 + 2];
                const float py2 = props[(size_t)p * 4 + 3];
                const float wq = __fsub_rn(px2, px1);
                const float hq = __fsub_rn(py2, py1);
                const float cxq = __fadd_rn(px1, __fmul_rn(0.5f, wq));
                const float cyq = __fadd_rn(py1, __fmul_rn(0.5f, hq));

                const float pcx = __fadd_rn(__fmul_rn(dx, wq), cxq);
                const float pcy = __fadd_rn(__fmul_rn(dy, hq), cyq);
                const float ew = (float)exp((double)dw);
                const float eh = (float)exp((double)dh);
                const float pw = __fmul_rn(ew, wq);
                const float ph = __fmul_rn(eh, hq);

                const float hw = __fmul_rn(0.5f, pw);
                const float hh = __fmul_rn(0.5f, ph);
                const float bx1 = fminf(fmaxf(__fsub_rn(pcx, hw), 0.f), IMG_W);
                const float by1 = fminf(fmaxf(__fsub_rn(pcy, hh), 0.f), IMG_H);
                const float bx2 = fminf(fmaxf(__fadd_rn(pcx, hw), 0.f), IMG_W);
                const float by2 = fminf(fmaxf(__fadd_rn(pcy, hh), 0.f), IMG_H);

                cx1[g] = bx1; cy1[g] = by1; cx2[g] = bx2; cy2[g] = by2;
                if (!(__fsub_rn(bx2, bx1) >= MIN_SZ && __fsub_rn(by2, by1) >= MIN_SZ)) {
                    cs[g] = -INFINITY;
                }
            }
        }
    }
}

// ---------------------------------------------------------------------------
// Kernel 3: per-(image,class) greedy NMS — one wave per (b,c) pair.
// (unchanged — bit-exact)
// ---------------------------------------------------------------------------
__global__ __launch_bounds__(64) void nms_class(
    const float* __restrict__ c_x1, const float* __restrict__ c_y1,
    const float* __restrict__ c_x2, const float* __restrict__ c_y2,
    const float* __restrict__ c_s, const int* __restrict__ c_lab,
    const int* __restrict__ c_orig, const int* __restrict__ cnt,
    ull* __restrict__ skey, float* __restrict__ sx1v, float* __restrict__ sy1v,
    float* __restrict__ sx2v, float* __restrict__ sy2v,
    int* __restrict__ slabv, int* __restrict__ scnt)
{
    const int blk = blockIdx.x;
    const int b = blk / (CC_ - 1);
    const int c = 1 + (blk - b * (CC_ - 1));
    const int lane = threadIdx.x;

    __shared__ ull kk[CLS_CAP];
    __shared__ float x1s[CLS_CAP], y1s[CLS_CAP], x2s[CLS_CAP], y2s[CLS_CAP];

    const int n = min(cnt[b], CAP_);

    int mcnt = 0;
    for (int i0 = 0; i0 < n; i0 += 64) {
        const int i = i0 + lane;
        bool take = false;
        float s = 0.f; int so = 0; int g = 0;
        if (i < n) {
            g = b * CAP_ + i;
            if (c_lab[g] == c) {
                s = c_s[g];
                if (s > 0.f) { take = true; so = c_orig[g]; }
            }
        }
        const ull bal = __ballot(take);
        if (take) {
            const int pos = mcnt + __popcll(bal & ((1ull << lane) - 1ull));
            if (pos < CLS_CAP) {
                kk[pos] = ((ull)__float_as_uint(s) << 32) |
                          (unsigned int)(0x7FFFFFFF - so);
                x1s[pos] = c_x1[g]; y1s[pos] = c_y1[g];
                x2s[pos] = c_x2[g]; y2s[pos] = c_y2[g];
            }
        }
        mcnt += (int)__popcll(bal);
    }
    mcnt = min(mcnt, CLS_CAP);
    if (mcnt == 0) return;
    __syncthreads();

    while (true) {
        ull best = 0ull;
        for (int i = lane; i < mcnt; i += 64) best = (kk[i] > best) ? kk[i] : best;
#pragma unroll
        for (int off = 32; off > 0; off >>= 1) {
            const ull o = __shfl_xor(best, off);
            best = (o > best) ? o : best;
        }
        if (best == 0ull) break;

        int wsl = -1;
        for (int i = lane; i < mcnt; i += 64) if (kk[i] == best) wsl = i;
        const ull bal = __ballot(wsl >= 0);
        const int wlane = (int)__ffsll((long long)bal) - 1;
        wsl = __shfl(wsl, wlane);

        const float wx1 = x1s[wsl], wy1 = y1s[wsl];
        const float wx2 = x2s[wsl], wy2 = y2s[wsl];

        if (lane == 0) {
            const int sp = atomicAdd(&scnt[b], 1);
            if (sp < SURV_CAP) {
                const int sg = b * SURV_CAP + sp;
                skey[sg] = best;
                sx1v[sg] = wx1; sy1v[sg] = wy1;
                sx2v[sg] = wx2; sy2v[sg] = wy2;
                slabv[sg] = c;
            }
        }

        const float off = __fmul_rn((float)c, OFF_);
        const float ax1 = __fadd_rn(wx1, off), ay1 = __fadd_rn(wy1, off);
        const float ax2 = __fadd_rn(wx2, off), ay2 = __fadd_rn(wy2, off);
        const float a1 = __fmul_rn(__fsub_rn(ax2, ax1), __fsub_rn(ay2, ay1));
        for (int i = lane; i < mcnt; i += 64) {
            if (kk[i] == 0ull) continue;
            const float bx1 = __fadd_rn(x1s[i], off), by1 = __fadd_rn(y1s[i], off);
            const float bx2 = __fadd_rn(x2s[i], off), by2 = __fadd_rn(y2s[i], off);
            const float ix1 = fmaxf(ax1, bx1), iy1 = fmaxf(ay1, by1);
            const float ix2 = fminf(ax2, bx2), iy2 = fminf(ay2, by2);
            const float inter = __fmul_rn(fmaxf(__fsub_rn(ix2, ix1), 0.f),
                                          fmaxf(__fsub_rn(iy2, iy1), 0.f));
            const float a2 = __fmul_rn(__fsub_rn(bx2, bx1), __fsub_rn(by2, by1));
            const float den = __fadd_rn(__fsub_rn(__fadd_rn(a1, a2), inter), 1e-9f);
            const float iou = __fdiv_rn(inter, den);
            if (iou > NMS_TH) kk[i] = 0ull;
        }
        __syncthreads();
    }
}

// ---------------------------------------------------------------------------
// Kernel 4: per-image merge — bitonic sort survivors by key (desc), emit
// top-100 in order. (unchanged — bit-exact)
// ---------------------------------------------------------------------------
__global__ __launch_bounds__(256) void nms_merge(
    const ull* __restrict__ skey, const float* __restrict__ sx1v,
    const float* __restrict__ sy1v, const float* __restrict__ sx2v,
    const float* __restrict__ sy2v, const int* __restrict__ slabv,
    const int* __restrict__ scnt, float* __restrict__ out)
{
    const int b = blockIdx.x;
    const int t = threadIdx.x;

    __shared__ ull k_[SURV_CAP];
    __shared__ int id_[SURV_CAP];

    const int m = min(scnt[b], SURV_CAP);
    int N2 = 128;
    while (N2 < m) N2 <<= 1;

    for (int i = t; i < N2; i += 256) {
        k_[i] = (i < m) ? skey[b * SURV_CAP + i] : 0ull;
        id_[i] = i;
    }
    __syncthreads();

    for (int ksz = 2; ksz <= N2; ksz <<= 1) {
        for (int j = ksz >> 1; j > 0; j >>= 1) {
            for (int i = t; i < N2; i += 256) {
                const int ixj = i ^ j;
                if (ixj > i) {
                    const ull a = k_[i], cc = k_[ixj];
                    const bool desc = ((i & ksz) == 0);
                    if (desc ? (a < cc) : (a > cc)) {
                        k_[i] = cc; k_[ixj] = a;
                        const int tmp = id_[i]; id_[i] = id_[ixj]; id_[ixj] = tmp;
                    }
                }
            }
            __syncthreads();
        }
    }

    const int boxes_base = 0;
    const int scores_base = BB_ * DETS_ * 4;
    const int labels_base = BB_ * DETS_ * 5;

    for (int r = t; r < DETS_; r += 256) {
        const ull key = (r < N2) ? k_[r] : 0ull;
        float* bo = out + boxes_base + (size_t)(b * DETS_ + r) * 4;
        if (key != 0ull) {
            const int sg = b * SURV_CAP + id_[r];
            bo[0] = sx1v[sg]; bo[1] = sy1v[sg];
            bo[2] = sx2v[sg]; bo[3] = sy2v[sg];
            out[scores_base + b * DETS_ + r] = __uint_as_float((unsigned)(key >> 32));
            out[labels_base + b * DETS_ + r] = (float)slabv[sg];
        } else {
            bo[0] = 0.f; bo[1] = 0.f; bo[2] = 0.f; bo[3] = 0.f;
            out[scores_base + b * DETS_ + r] = 0.f;
            out[labels_base + b * DETS_ + r] = 0.f;
        }
    }
}

// ---------------------------------------------------------------------------
extern "C" void kernel_launch(void* const* d_in, const int* in_sizes, int n_in,
                              void* d_out, int out_size, void* d_ws, size_t ws_size,
                              hipStream_t stream)
{
    const float* feat  = (const float*)d_in[0];
    const float* Wc    = (const float*)d_in[1];
    const float* bc    = (const float*)d_in[2];
    const float* Wb    = (const float*)d_in[3];
    const float* bb    = (const float*)d_in[4];
    const float* props = (const float*)d_in[5];
    for (int i = 0; i < n_in; ++i) {
        const float* q = (const float*)d_in[i];
        switch (in_sizes[i]) {
            case 16384000: feat  = q; break;  // [16000,1024]
            case 93184:    Wc    = q; break;  // [1024,91]
            case 91:       bc    = q; break;
            case 372736:   Wb    = q; break;  // [1024,364]
            case 364:      bb    = q; break;
            case 64000:    props = q; break;  // [16,1000,4]
        }
    }
    float* out = (float*)d_out;

    char* ws = (char*)d_ws;
    int*   cnt    = (int*)ws;            // 16 ints
    int*   scnt   = (int*)(ws + 64);     // 16 ints
    int*   nrowsp = (int*)(ws + 128);    // 1 int
    float* cs    = (float*)(ws + 256);
    int*   clab  = (int*)(cs + CAND_MAX);
    int*   corig = clab + CAND_MAX;
    int*   cpidx = corig + CAND_MAX;
    float* cx1   = (float*)(cpidx + CAND_MAX);
    float* cy1   = cx1 + CAND_MAX;
    float* cx2   = cy1 + CAND_MAX;
    float* cy2   = cx2 + CAND_MAX;
    ull*   skey  = (ull*)(cy2 + CAND_MAX);
    float* sx1v  = (float*)(skey + (size_t)BB_ * SURV_CAP);
    float* sy1v  = sx1v + (size_t)BB_ * SURV_CAP;
    float* sx2v  = sy1v + (size_t)BB_ * SURV_CAP;
    float* sy2v  = sx2v + (size_t)BB_ * SURV_CAP;
    int*   slabv = (int*)(sy2v + (size_t)BB_ * SURV_CAP);
    int*   rowlist = slabv + (size_t)BB_ * SURV_CAP;   // 16000 ints
    float* Wbt   = (float*)(rowlist + 16384);          // 91*4*1024 floats

    const size_t need = ((char*)(Wbt + CC_ * 4 * FF_)) - ws;
    const bool useT = (ws_size >= need);

    hipMemsetAsync(ws, 0, 256, stream);   // zero cnt + scnt + nrows

    if (useT)
        wb_transpose<<<(CC_ * 4 * FF_ + 255) / 256, 256, 0, stream>>>(Wb, Wbt);

    prepass_rows<<<BB_ * PP_ / 32, 512, 0, stream>>>(feat, Wc, bc,
        rowlist, nrowsp);

    if (useT)
        logits_fp64_rows<true><<<BB_ * PP_ / 8, 512, 0, stream>>>(
            feat, Wc, bc, Wb, Wbt, bb, props, rowlist, nrowsp,
            cs, clab, corig, cpidx, cnt, cx1, cy1, cx2, cy2);
    else
        logits_fp64_rows<false><<<BB_ * PP_ / 8, 512, 0, stream>>>(
            feat, Wc, bc, Wb, Wbt, bb, props, rowlist, nrowsp,
            cs, clab, corig, cpidx, cnt, cx1, cy1, cx2, cy2);

    nms_class<<<BB_ * (CC_ - 1), 64, 0, stream>>>(
        cx1, cy1, cx2, cy2, cs, clab, corig, cnt,
        skey, sx1v, sy1v, sx2v, sy2v, slabv, scnt);

    nms_merge<<<BB_, 256, 0, stream>>>(
        skey, sx1v, sy1v, sx2v, sy2v, slabv, scnt, out);
}

// Round 16
// 251.046 us; speedup vs baseline: 1.3263x; 1.1489x over previous
//
#include <hip/hip_runtime.h>
#include <hip/hip_bf16.h>
#include <math.h>

typedef unsigned long long ull;
typedef __attribute__((ext_vector_type(8))) short bf16x8;
typedef __attribute__((ext_vector_type(4))) float f32x4;

// Problem constants
#define BB_ 16          // images
#define PP_ 1000        // proposals per image
#define CC_ 91          // classes incl background
#define FF_ 1024        // feature dim
#define DETS_ 100
#define CAP_ 2048       // candidate capacity per image (measured ~320)
#define CAND_MAX (BB_ * CAP_)
#define SURV_CAP 2048   // NMS-survivor capacity per image
#define CLS_CAP 256     // per-(image,class) candidate capacity
#define BLK_CAND 720    // 8 rows x 90 classes: hard upper bound per block
#define IMG_W 800.0f
#define IMG_H 800.0f
#define OFF_ 802.0f     // max(H,W)+2
#define SCORE_TH 0.05f
#define PRE_TH 0.042f   // bf16-MFMA prepass cutoff: 8e-3 margin >> ~1e-3 worst err
#define NMS_TH 0.5f
#define MIN_SZ 0.01f
#define BBOX_CLIP_D 4.135166556742356   // log(1000/16)

// ---------------------------------------------------------------------------
// Kernel 0a: Wb [1024][364] -> Wbt [91][4][1024] (exact fp32 copy)
// ---------------------------------------------------------------------------
__global__ __launch_bounds__(256) void wb_transpose(
    const float* __restrict__ Wb, float* __restrict__ Wbt)
{
    const int idx = blockIdx.x * 256 + threadIdx.x;
    if (idx >= CC_ * 4 * FF_) return;
    const int c = idx >> 12;
    const int j = (idx >> 10) & 3;
    const int k = idx & 1023;
    if (c < 1) { Wbt[idx] = 0.f; return; }
    Wbt[idx] = Wb[(size_t)k * (CC_ * 4) + 4 * c + j];
}

// ---------------------------------------------------------------------------
// Kernel 0b: Wc [1024][91] -> Wct bf16 [96][1024] (transposed, zero-padded)
// ---------------------------------------------------------------------------
__global__ __launch_bounds__(256) void wc_bf16_t(
    const float* __restrict__ Wc, ushort* __restrict__ Wct)
{
    const int idx = blockIdx.x * 256 + threadIdx.x;
    if (idx >= 96 * FF_) return;
    const int c = idx >> 10, k = idx & 1023;
    const float v = (c < CC_) ? Wc[(size_t)k * CC_ + c] : 0.f;
    const unsigned u = __float_as_uint(v);
    Wct[idx] = (ushort)((u + 0x8000u) >> 16);
}

// ---------------------------------------------------------------------------
// Kernel 1a: MFMA bf16 prepass — 32 rows x 96 cols per block, 500 blocks,
// 256 threads (4 waves), v_mfma_f32_16x16x32_bf16, 3 acc/wave. A converted
// to bf16 in-register at staging (RNE). Emits rows with approx max fg
// score > PRE_TH (margin >> bf16 error) into rowlist.
// ---------------------------------------------------------------------------
__global__ __launch_bounds__(256) void prepass_mfma(
    const float* __restrict__ A, const ushort* __restrict__ Wct,
    const float* __restrict__ bc,
    int* __restrict__ rowlist, int* __restrict__ nrowsp)
{
    __shared__ union __align__(16) SM {
        struct { ushort As[32][40]; ushort Bt[96][40]; } t;  // 10.0 KB
        float Ssc[32][97];                                   // 12.4 KB
    } sm;

    const int tid = threadIdx.x;
    const int row0 = blockIdx.x * 32;
    const int lane = tid & 63;
    const int w = tid >> 6;
    const int rowOff = (w & 1) * 16;
    const int colOff = (w >> 1) * 48;

    // A staging: 32 rows x 32 k, float4 -> 4 bf16 per thread
    const int arow = tid >> 3;         // 0..31
    const int ak4 = (tid & 7) * 4;     // 0,4..28
    // B staging: threads 0..191: col = tid>>1, k-half = (tid&1)*16
    const int bcol = tid >> 1;
    const int bkh = (tid & 1) * 16;

    f32x4 acc0 = {0.f, 0.f, 0.f, 0.f};
    f32x4 acc1 = {0.f, 0.f, 0.f, 0.f};
    f32x4 acc2 = {0.f, 0.f, 0.f, 0.f};

    // prologue prefetch (k0 = 0)
    float4 avP = *(const float4*)(A + (size_t)(row0 + arow) * FF_ + ak4);
    uint4 bvP0 = make_uint4(0, 0, 0, 0), bvP1 = make_uint4(0, 0, 0, 0);
    if (tid < 192) {
        const ushort* src = Wct + (size_t)bcol * FF_ + bkh;
        bvP0 = *(const uint4*)(src);
        bvP1 = *(const uint4*)(src + 8);
    }

    for (int k0 = 0; k0 < FF_; k0 += 32) {
        // stage current tiles (A converted fp32->bf16 RNE here)
        {
            const unsigned b0 = __float_as_uint(avP.x), b1 = __float_as_uint(avP.y);
            const unsigned b2 = __float_as_uint(avP.z), b3 = __float_as_uint(avP.w);
            const unsigned u0 = ((b0 + 0x8000u) >> 16) | (((b1 + 0x8000u) >> 16) << 16);
            const unsigned u1 = ((b2 + 0x8000u) >> 16) | (((b3 + 0x8000u) >> 16) << 16);
            *(uint2*)&sm.t.As[arow][ak4] = make_uint2(u0, u1);
        }
        if (tid < 192) {
            *(uint4*)&sm.t.Bt[bcol][bkh] = bvP0;
            *(uint4*)&sm.t.Bt[bcol][bkh + 8] = bvP1;
        }

        // prefetch next tiles
        const int kn = k0 + 32;
        if (kn < FF_) {
            avP = *(const float4*)(A + (size_t)(row0 + arow) * FF_ + kn + ak4);
            if (tid < 192) {
                const ushort* src = Wct + (size_t)bcol * FF_ + kn + bkh;
                bvP0 = *(const uint4*)(src);
                bvP1 = *(const uint4*)(src + 8);
            }
        }
        __syncthreads();

        // fragments: A[m][k]: m=lane&15 (+rowOff), k=(lane>>4)*8+e (contig)
        //            B[k][n]: n=lane&15 (+tile), k=(lane>>4)*8+e -> from Bt[n][k]
        const bf16x8 aF  = *(const bf16x8*)&sm.t.As[rowOff + (lane & 15)][(lane >> 4) * 8];
        const bf16x8 bF0 = *(const bf16x8*)&sm.t.Bt[colOff +  0 + (lane & 15)][(lane >> 4) * 8];
        const bf16x8 bF1 = *(const bf16x8*)&sm.t.Bt[colOff + 16 + (lane & 15)][(lane >> 4) * 8];
        const bf16x8 bF2 = *(const bf16x8*)&sm.t.Bt[colOff + 32 + (lane & 15)][(lane >> 4) * 8];
        acc0 = __builtin_amdgcn_mfma_f32_16x16x32_bf16(aF, bF0, acc0, 0, 0, 0);
        acc1 = __builtin_amdgcn_mfma_f32_16x16x32_bf16(aF, bF1, acc1, 0, 0, 0);
        acc2 = __builtin_amdgcn_mfma_f32_16x16x32_bf16(aF, bF2, acc2, 0, 0, 0);
        __syncthreads();
    }

    // write logits to Ssc overlay (tiles dead after final barrier)
    {
        const int r0 = rowOff + (lane >> 4) * 4;
        const int cb = colOff + (lane & 15);
#pragma unroll
        for (int reg = 0; reg < 4; ++reg) {
            const int row = r0 + reg;
            int c = cb;
            if (c < CC_) sm.Ssc[row][c] = acc0[reg] + bc[c];
            c = cb + 16;
            if (c < CC_) sm.Ssc[row][c] = acc1[reg] + bc[c];
            c = cb + 32;
            if (c < CC_) sm.Ssc[row][c] = acc2[reg] + bc[c];
        }
    }
    __syncthreads();

    // per-row filter: max fg approx score vs PRE_TH
    if (tid < 32) {
        float m_all = sm.Ssc[tid][0];
        float m_fg = -INFINITY;
        for (int c = 1; c < CC_; ++c) {
            const float lv = sm.Ssc[tid][c];
            m_all = fmaxf(m_all, lv);
            m_fg = fmaxf(m_fg, lv);
        }
        float denom = 0.f;
        for (int c = 0; c < CC_; ++c) denom += expf(sm.Ssc[tid][c] - m_all);
        const float maxsc = expf(m_fg - m_all) / denom;
        if (maxsc > PRE_TH) {
            const int pos = atomicAdd(nrowsp, 1);
            rowlist[pos] = row0 + tid;   // capacity 16000: cannot overflow
        }
    }
}

// ---------------------------------------------------------------------------
// Kernel 1b (FUSED): fp64 logits on gathered rows + fused decode.
// (byte-identical to R15 — bit-exact selection math)
// ---------------------------------------------------------------------------
template<bool USE_T>
__global__ __launch_bounds__(512) void logits_fp64_rows(
    const float* __restrict__ A, const float* __restrict__ Wc,
    const float* __restrict__ bc,
    const float* __restrict__ Wb, const float* __restrict__ Wbt,
    const float* __restrict__ bb, const float* __restrict__ props,
    const int* __restrict__ rowlist, const int* __restrict__ nrowsp,
    float* __restrict__ cs, int* __restrict__ clab,
    int* __restrict__ corig, int* __restrict__ cpidx,
    int* __restrict__ cnt,
    float* __restrict__ cx1, float* __restrict__ cy1,
    float* __restrict__ cx2, float* __restrict__ cy2)
{
    const int nr = *nrowsp;
    const int row0 = blockIdx.x * 8;
    if (row0 >= nr) return;

    __shared__ union __align__(16) SM {
        struct { float Af[2][16][12]; float Bs[2][16][98]; } t;   // 14 KB
        struct { int cp[BLK_CAND]; int cc[BLK_CAND]; int cg[BLK_CAND]; } d;
    } sm;
    __shared__ __align__(16) double dcomb[256][3];  // 6 KB
    __shared__ float Ssc[8][97];                    // 3.1 KB
    __shared__ int ncand;

    const int tid = threadIdx.x;
    const int kg = tid >> 8;
    const int l = tid & 255;
    const int kbase = kg * 512;
    const int r = l >> 5;              // row 0..7
    const int c0 = (l & 31) * 3;       // col base 0..93

    if (tid == 0) ncand = 0;

    const int aslot = l >> 2;          // 0..7 (l<32)
    const int akq = (l & 3) * 4;
    const float* Arow = nullptr;
    if (l < 32) {
        const int ridx = min(row0 + aslot, nr - 1);
        Arow = A + (size_t)rowlist[ridx] * FF_ + kbase;
    }
    const int bk = l >> 4;
    const int bn = (l & 15) * 6;

    double acc[3] = {0.0, 0.0, 0.0};

    float4 avP = make_float4(0.f, 0.f, 0.f, 0.f);
    if (l < 32) avP = *reinterpret_cast<const float4*>(Arow + akq);
    float bvP[6];
#pragma unroll
    for (int jj = 0; jj < 6; ++jj) {
        const int c = bn + jj;
        bvP[jj] = (c < CC_) ? Wc[(size_t)(kbase + bk) * CC_ + c] : 0.f;
    }

    for (int k0 = 0; k0 < 512; k0 += 16) {
        if (l < 32) {
            sm.t.Af[kg][akq + 0][aslot] = avP.x;
            sm.t.Af[kg][akq + 1][aslot] = avP.y;
            sm.t.Af[kg][akq + 2][aslot] = avP.z;
            sm.t.Af[kg][akq + 3][aslot] = avP.w;
        }
#pragma unroll
        for (int jj = 0; jj < 6; ++jj) sm.t.Bs[kg][bk][bn + jj] = bvP[jj];

        const int kn = k0 + 16;
        if (kn < 512) {
            if (l < 32)
                avP = *reinterpret_cast<const float4*>(Arow + kn + akq);
#pragma unroll
            for (int jj = 0; jj < 6; ++jj) {
                const int c = bn + jj;
                bvP[jj] = (c < CC_) ? Wc[(size_t)(kbase + kn + bk) * CC_ + c] : 0.f;
            }
        }
        __syncthreads();

#pragma unroll
        for (int k = 0; k < 16; ++k) {
            const double a0 = (double)sm.t.Af[kg][k][r];
            const double b0 = (double)sm.t.Bs[kg][k][c0 + 0];
            const double b1 = (double)sm.t.Bs[kg][k][c0 + 1];
            const double b2 = (double)sm.t.Bs[kg][k][c0 + 2];
            acc[0] += a0 * b0;
            acc[1] += a0 * b1;
            acc[2] += a0 * b2;
        }
        __syncthreads();
    }

    if (kg == 1) {
#pragma unroll
        for (int j = 0; j < 3; ++j) dcomb[l][j] = acc[j];
    }
    __syncthreads();
    if (kg == 0) {
#pragma unroll
        for (int j = 0; j < 3; ++j) {
            const int c = c0 + j;
            if (c < CC_) {
                const double v = acc[j] + dcomb[l][j];
                Ssc[r][c] = __fadd_rn((float)v, bc[c]);
            }
        }
    }
    __syncthreads();

    {
        const int w = tid >> 6;
        const int lane = tid & 63;
        if (w < 8 && row0 + w < nr) {
            const int p = rowlist[row0 + w];
            const int b = p / PP_;
            const int pi = p - b * PP_;

            const float l1 = Ssc[w][lane];
            const float l2 = (lane < CC_ - 64) ? Ssc[w][lane + 64] : -INFINITY;
            float m = fmaxf(l1, l2);
#pragma unroll
            for (int off = 32; off > 0; off >>= 1)
                m = fmaxf(m, __shfl_xor(m, off));

            double d = exp((double)l1 - (double)m);
            if (lane < CC_ - 64) d += exp((double)l2 - (double)m);
#pragma unroll
            for (int off = 1; off < 64; off <<= 1)
                d += __shfl_xor(d, off);

#pragma unroll
            for (int q = 0; q < 2; ++q) {
                const int c = lane + q * 64;
                if (c >= 1 && c < CC_) {
                    const double sd = exp((double)Ssc[w][c] - (double)m) / d;
                    const float score = (float)sd;
                    if (score > SCORE_TH) {
                        const int pos = atomicAdd(&cnt[b], 1);
                        if (pos < CAP_) {
                            const int g = b * CAP_ + pos;
                            cs[g] = score;
                            clab[g] = c;
                            corig[g] = pi * (CC_ - 1) + (c - 1);
                            cpidx[g] = p;
                            const int slot = atomicAdd(&ncand, 1);
                            if (slot < BLK_CAND) {
                                sm.d.cp[slot] = p;
                                sm.d.cc[slot] = c;
                                sm.d.cg[slot] = g;
                            }
                        }
                    }
                }
            }
        }
    }
    __syncthreads();

    {
        const int w = tid >> 6;
        const int lane = tid & 63;
        const int nc = min(ncand, BLK_CAND);
        for (int ci = w; ci < nc; ci += 8) {
            const int p = sm.d.cp[ci];
            const int c = sm.d.cc[ci];
            const int g = sm.d.cg[ci];

            const float* fr = A + (size_t)p * FF_;
            double a0 = 0.0, a1 = 0.0, a2 = 0.0, a3 = 0.0;
            if (USE_T) {
                const float* w0 = Wbt + (size_t)c * 4096;
                for (int k = lane; k < FF_; k += 64) {
                    const double f = (double)fr[k];
                    a0 += f * (double)w0[k];
                    a1 += f * (double)w0[1024 + k];
                    a2 += f * (double)w0[2048 + k];
                    a3 += f * (double)w0[3072 + k];
                }
            } else {
                const float* wb0 = Wb + 4 * c;
                for (int k = lane; k < FF_; k += 64) {
                    const double f = (double)fr[k];
                    const float4 wv = *reinterpret_cast<const float4*>(
                        wb0 + (size_t)k * (CC_ * 4));
                    a0 += f * (double)wv.x; a1 += f * (double)wv.y;
                    a2 += f * (double)wv.z; a3 += f * (double)wv.w;
                }
            }
#pragma unroll
            for (int off = 32; off > 0; off >>= 1) {
                a0 += __shfl_xor(a0, off);
                a1 += __shfl_xor(a1, off);
                a2 += __shfl_xor(a2, off);
                a3 += __shfl_xor(a3, off);
            }

            if (lane == 0) {
                const float dx = __fadd_rn((float)a0, bb[4 * c + 0]);
                const float dy = __fadd_rn((float)a1, bb[4 * c + 1]);
                const float clipf = (float)BBOX_CLIP_D;
                const float dw = fminf(__fadd_rn((float)a2, bb[4 * c + 2]), clipf);
                const float dh = fminf(__fadd_rn((float)a3, bb[4 * c + 3]), clipf);

                const float px1 = props[(size_t)p * 4 + 0];
                const float py1 = props[(size_t)p * 4 + 1];
                const float px2 = props[(size_t)p * 4 + 2];
                const float py2 = props[(size_t)p * 4 + 3];
                const float wq = __fsub_rn(px2, px1);
                const float hq = __fsub_rn(py2, py1);
                const float cxq = __fadd_rn(px1, __fmul_rn(0.5f, wq));
                const float cyq = __fadd_rn(py1, __fmul_rn(0.5f, hq));

                const float pcx = __fadd_rn(__fmul_rn(dx, wq), cxq);
                const float pcy = __fadd_rn(__fmul_rn(dy, hq), cyq);
                const float ew = (float)exp((double)dw);
                const float eh = (float)exp((double)dh);
                const float pw = __fmul_rn(ew, wq);
                const float ph = __fmul_rn(eh, hq);

                const float hw = __fmul_rn(0.5f, pw);
                const float hh = __fmul_rn(0.5f, ph);
                const float bx1 = fminf(fmaxf(__fsub_rn(pcx, hw), 0.f), IMG_W);
                const float by1 = fminf(fmaxf(__fsub_rn(pcy, hh), 0.f), IMG_H);
                const float bx2 = fminf(fmaxf(__fadd_rn(pcx, hw), 0.f), IMG_W);
                const float by2 = fminf(fmaxf(__fadd_rn(pcy, hh), 0.f), IMG_H);

                cx1[g] = bx1; cy1[g] = by1; cx2[g] = bx2; cy2[g] = by2;
                if (!(__fsub_rn(bx2, bx1) >= MIN_SZ && __fsub_rn(by2, by1) >= MIN_SZ)) {
                    cs[g] = -INFINITY;
                }
            }
        }
    }
}

// ---------------------------------------------------------------------------
// Kernel 3: per-(image,class) greedy NMS — one wave per (b,c) pair.
// (unchanged — bit-exact)
// ---------------------------------------------------------------------------
__global__ __launch_bounds__(64) void nms_class(
    const float* __restrict__ c_x1, const float* __restrict__ c_y1,
    const float* __restrict__ c_x2, const float* __restrict__ c_y2,
    const float* __restrict__ c_s, const int* __restrict__ c_lab,
    const int* __restrict__ c_orig, const int* __restrict__ cnt,
    ull* __restrict__ skey, float* __restrict__ sx1v, float* __restrict__ sy1v,
    float* __restrict__ sx2v, float* __restrict__ sy2v,
    int* __restrict__ slabv, int* __restrict__ scnt)
{
    const int blk = blockIdx.x;
    const int b = blk / (CC_ - 1);
    const int c = 1 + (blk - b * (CC_ - 1));
    const int lane = threadIdx.x;

    __shared__ ull kk[CLS_CAP];
    __shared__ float x1s[CLS_CAP], y1s[CLS_CAP], x2s[CLS_CAP], y2s[CLS_CAP];

    const int n = min(cnt[b], CAP_);

    int mcnt = 0;
    for (int i0 = 0; i0 < n; i0 += 64) {
        const int i = i0 + lane;
        bool take = false;
        float s = 0.f; int so = 0; int g = 0;
        if (i < n) {
            g = b * CAP_ + i;
            if (c_lab[g] == c) {
                s = c_s[g];
                if (s > 0.f) { take = true; so = c_orig[g]; }
            }
        }
        const ull bal = __ballot(take);
        if (take) {
            const int pos = mcnt + __popcll(bal & ((1ull << lane) - 1ull));
            if (pos < CLS_CAP) {
                kk[pos] = ((ull)__float_as_uint(s) << 32) |
                          (unsigned int)(0x7FFFFFFF - so);
                x1s[pos] = c_x1[g]; y1s[pos] = c_y1[g];
                x2s[pos] = c_x2[g]; y2s[pos] = c_y2[g];
            }
        }
        mcnt += (int)__popcll(bal);
    }
    mcnt = min(mcnt, CLS_CAP);
    if (mcnt == 0) return;
    __syncthreads();

    while (true) {
        ull best = 0ull;
        for (int i = lane; i < mcnt; i += 64) best = (kk[i] > best) ? kk[i] : best;
#pragma unroll
        for (int off = 32; off > 0; off >>= 1) {
            const ull o = __shfl_xor(best, off);
            best = (o > best) ? o : best;
        }
        if (best == 0ull) break;

        int wsl = -1;
        for (int i = lane; i < mcnt; i += 64) if (kk[i] == best) wsl = i;
        const ull bal = __ballot(wsl >= 0);
        const int wlane = (int)__ffsll((long long)bal) - 1;
        wsl = __shfl(wsl, wlane);

        const float wx1 = x1s[wsl], wy1 = y1s[wsl];
        const float wx2 = x2s[wsl], wy2 = y2s[wsl];

        if (lane == 0) {
            const int sp = atomicAdd(&scnt[b], 1);
            if (sp < SURV_CAP) {
                const int sg = b * SURV_CAP + sp;
                skey[sg] = best;
                sx1v[sg] = wx1; sy1v[sg] = wy1;
                sx2v[sg] = wx2; sy2v[sg] = wy2;
                slabv[sg] = c;
            }
        }

        const float off = __fmul_rn((float)c, OFF_);
        const float ax1 = __fadd_rn(wx1, off), ay1 = __fadd_rn(wy1, off);
        const float ax2 = __fadd_rn(wx2, off), ay2 = __fadd_rn(wy2, off);
        const float a1 = __fmul_rn(__fsub_rn(ax2, ax1), __fsub_rn(ay2, ay1));
        for (int i = lane; i < mcnt; i += 64) {
            if (kk[i] == 0ull) continue;
            const float bx1 = __fadd_rn(x1s[i], off), by1 = __fadd_rn(y1s[i], off);
            const float bx2 = __fadd_rn(x2s[i], off), by2 = __fadd_rn(y2s[i], off);
            const float ix1 = fmaxf(ax1, bx1), iy1 = fmaxf(ay1, by1);
            const float ix2 = fminf(ax2, bx2), iy2 = fminf(ay2, by2);
            const float inter = __fmul_rn(fmaxf(__fsub_rn(ix2, ix1), 0.f),
                                          fmaxf(__fsub_rn(iy2, iy1), 0.f));
            const float a2 = __fmul_rn(__fsub_rn(bx2, bx1), __fsub_rn(by2, by1));
            const float den = __fadd_rn(__fsub_rn(__fadd_rn(a1, a2), inter), 1e-9f);
            const float iou = __fdiv_rn(inter, den);
            if (iou > NMS_TH) kk[i] = 0ull;
        }
        __syncthreads();
    }
}

// ---------------------------------------------------------------------------
// Kernel 4: per-image merge — bitonic sort survivors by key (desc), emit
// top-100 in order. (unchanged — bit-exact)
// ---------------------------------------------------------------------------
__global__ __launch_bounds__(256) void nms_merge(
    const ull* __restrict__ skey, const float* __restrict__ sx1v,
    const float* __restrict__ sy1v, const float* __restrict__ sx2v,
    const float* __restrict__ sy2v, const int* __restrict__ slabv,
    const int* __restrict__ scnt, float* __restrict__ out)
{
    const int b = blockIdx.x;
    const int t = threadIdx.x;

    __shared__ ull k_[SURV_CAP];
    __shared__ int id_[SURV_CAP];

    const int m = min(scnt[b], SURV_CAP);
    int N2 = 128;
    while (N2 < m) N2 <<= 1;

    for (int i = t; i < N2; i += 256) {
        k_[i] = (i < m) ? skey[b * SURV_CAP + i] : 0ull;
        id_[i] = i;
    }
    __syncthreads();

    for (int ksz = 2; ksz <= N2; ksz <<= 1) {
        for (int j = ksz >> 1; j > 0; j >>= 1) {
            for (int i = t; i < N2; i += 256) {
                const int ixj = i ^ j;
                if (ixj > i) {
                    const ull a = k_[i], cc = k_[ixj];
                    const bool desc = ((i & ksz) == 0);
                    if (desc ? (a < cc) : (a > cc)) {
                        k_[i] = cc; k_[ixj] = a;
                        const int tmp = id_[i]; id_[i] = id_[ixj]; id_[ixj] = tmp;
                    }
                }
            }
            __syncthreads();
        }
    }

    const int boxes_base = 0;
    const int scores_base = BB_ * DETS_ * 4;
    const int labels_base = BB_ * DETS_ * 5;

    for (int r = t; r < DETS_; r += 256) {
        const ull key = (r < N2) ? k_[r] : 0ull;
        float* bo = out + boxes_base + (size_t)(b * DETS_ + r) * 4;
        if (key != 0ull) {
            const int sg = b * SURV_CAP + id_[r];
            bo[0] = sx1v[sg]; bo[1] = sy1v[sg];
            bo[2] = sx2v[sg]; bo[3] = sy2v[sg];
            out[scores_base + b * DETS_ + r] = __uint_as_float((unsigned)(key >> 32));
            out[labels_base + b * DETS_ + r] = (float)slabv[sg];
        } else {
            bo[0] = 0.f; bo[1] = 0.f; bo[2] = 0.f; bo[3] = 0.f;
            out[scores_base + b * DETS_ + r] = 0.f;
            out[labels_base + b * DETS_ + r] = 0.f;
        }
    }
}

// ---------------------------------------------------------------------------
extern "C" void kernel_launch(void* const* d_in, const int* in_sizes, int n_in,
                              void* d_out, int out_size, void* d_ws, size_t ws_size,
                              hipStream_t stream)
{
    const float* feat  = (const float*)d_in[0];
    const float* Wc    = (const float*)d_in[1];
    const float* bc    = (const float*)d_in[2];
    const float* Wb    = (const float*)d_in[3];
    const float* bb    = (const float*)d_in[4];
    const float* props = (const float*)d_in[5];
    for (int i = 0; i < n_in; ++i) {
        const float* q = (const float*)d_in[i];
        switch (in_sizes[i]) {
            case 16384000: feat  = q; break;  // [16000,1024]
            case 93184:    Wc    = q; break;  // [1024,91]
            case 91:       bc    = q; break;
            case 372736:   Wb    = q; break;  // [1024,364]
            case 364:      bb    = q; break;
            case 64000:    props = q; break;  // [16,1000,4]
        }
    }
    float* out = (float*)d_out;

    char* ws = (char*)d_ws;
    int*   cnt    = (int*)ws;            // 16 ints
    int*   scnt   = (int*)(ws + 64);     // 16 ints
    int*   nrowsp = (int*)(ws + 128);    // 1 int
    float* cs    = (float*)(ws + 256);
    int*   clab  = (int*)(cs + CAND_MAX);
    int*   corig = clab + CAND_MAX;
    int*   cpidx = corig + CAND_MAX;
    float* cx1   = (float*)(cpidx + CAND_MAX);
    float* cy1   = cx1 + CAND_MAX;
    float* cx2   = cy1 + CAND_MAX;
    float* cy2   = cx2 + CAND_MAX;
    ull*   skey  = (ull*)(cy2 + CAND_MAX);
    float* sx1v  = (float*)(skey + (size_t)BB_ * SURV_CAP);
    float* sy1v  = sx1v + (size_t)BB_ * SURV_CAP;
    float* sx2v  = sy1v + (size_t)BB_ * SURV_CAP;
    float* sy2v  = sx2v + (size_t)BB_ * SURV_CAP;
    int*   slabv = (int*)(sy2v + (size_t)BB_ * SURV_CAP);
    int*   rowlist = slabv + (size_t)BB_ * SURV_CAP;   // 16000 ints (pad 16384)
    ushort* Wct  = (ushort*)(rowlist + 16384);         // 96*1024 bf16 (196 KB)
    float* Wbt   = (float*)(Wct + 96 * FF_);           // 91*4*1024 fp32 (1.5 MB)

    const size_t need = ((char*)(Wbt + CC_ * 4 * FF_)) - ws;
    const bool useT = (ws_size >= need);

    hipMemsetAsync(ws, 0, 256, stream);   // zero cnt + scnt + nrows

    wc_bf16_t<<<(96 * FF_ + 255) / 256, 256, 0, stream>>>(Wc, Wct);
    if (useT)
        wb_transpose<<<(CC_ * 4 * FF_ + 255) / 256, 256, 0, stream>>>(Wb, Wbt);

    prepass_mfma<<<BB_ * PP_ / 32, 256, 0, stream>>>(feat, Wct, bc,
        rowlist, nrowsp);

    if (useT)
        logits_fp64_rows<true><<<BB_ * PP_ / 8, 512, 0, stream>>>(
            feat, Wc, bc, Wb, Wbt, bb, props, rowlist, nrowsp,
            cs, clab, corig, cpidx, cnt, cx1, cy1, cx2, cy2);
    else
        logits_fp64_rows<false><<<BB_ * PP_ / 8, 512, 0, stream>>>(
            feat, Wc, bc, Wb, Wbt, bb, props, rowlist, nrowsp,
            cs, clab, corig, cpidx, cnt, cx1, cy1, cx2, cy2);

    nms_class<<<BB_ * (CC_ - 1), 64, 0, stream>>>(
        cx1, cy1, cx2, cy2, cs, clab, corig, cnt,
        skey, sx1v, sy1v, sx2v, sy2v, slabv, scnt);

    nms_merge<<<BB_, 256, 0, stream>>>(
        skey, sx1v, sy1v, sx2v, sy2v, slabv, scnt, out);
}

// Round 17
// 240.337 us; speedup vs baseline: 1.3854x; 1.0446x over previous
//
#include <hip/hip_runtime.h>
#include <hip/hip_bf16.h>
#include <math.h>

typedef unsigned long long ull;
typedef __attribute__((ext_vector_type(8))) short bf16x8;
typedef __attribute__((ext_vector_type(4))) float f32x4;

// Problem constants
#define BB_ 16          // images
#define PP_ 1000        // proposals per image
#define CC_ 91          // classes incl background
#define FF_ 1024        // feature dim
#define DETS_ 100
#define CAP_ 2048       // candidate capacity per image (measured ~320)
#define CAND_MAX (BB_ * CAP_)
#define SURV_CAP 2048   // NMS-survivor capacity per image
#define CLS_CAP 256     // per-(image,class) candidate capacity
#define BLK_CAND 720    // 8 rows x 90 classes: hard upper bound per block
#define IMG_W 800.0f
#define IMG_H 800.0f
#define OFF_ 802.0f     // max(H,W)+2
#define SCORE_TH 0.05f
#define PRE_TH 0.048f   // split-bf16 prepass: 2e-3 margin >> ~2e-4 worst err
#define NMS_TH 0.5f
#define MIN_SZ 0.01f
#define BBOX_CLIP_D 4.135166556742356   // log(1000/16)

__device__ __forceinline__ ushort bf16_hi(float v) {
    return (ushort)((__float_as_uint(v) + 0x8000u) >> 16);
}

// ---------------------------------------------------------------------------
// Kernel 0a: Wb [1024][364] -> Wbt [91][4][1024] (exact fp32 copy)
// ---------------------------------------------------------------------------
__global__ __launch_bounds__(256) void wb_transpose(
    const float* __restrict__ Wb, float* __restrict__ Wbt)
{
    const int idx = blockIdx.x * 256 + threadIdx.x;
    if (idx >= CC_ * 4 * FF_) return;
    const int c = idx >> 12;
    const int j = (idx >> 10) & 3;
    const int k = idx & 1023;
    if (c < 1) { Wbt[idx] = 0.f; return; }
    Wbt[idx] = Wb[(size_t)k * (CC_ * 4) + 4 * c + j];
}

// ---------------------------------------------------------------------------
// Kernel 0b: Wc [1024][91] -> split-bf16 transposed Wct_h/Wct_l [96][1024]
// ---------------------------------------------------------------------------
__global__ __launch_bounds__(256) void wc_bf16_split(
    const float* __restrict__ Wc, ushort* __restrict__ Wcth,
    ushort* __restrict__ Wctl)
{
    const int idx = blockIdx.x * 256 + threadIdx.x;
    if (idx >= 96 * FF_) return;
    const int c = idx >> 10, k = idx & 1023;
    const float v = (c < CC_) ? Wc[(size_t)k * CC_ + c] : 0.f;
    const ushort h = bf16_hi(v);
    const float hf = __uint_as_float(((unsigned)h) << 16);
    Wcth[idx] = h;
    Wctl[idx] = bf16_hi(v - hf);
}

// ---------------------------------------------------------------------------
// Kernel 1a: split-bf16 MFMA prepass — 32 rows x 96 cols per block, 500
// blocks, 256 threads (4 waves), 9x v_mfma_f32_16x16x32_bf16 per k-step
// (ah*bh + ah*bl + al*bh). fp32-grade logits; PRE_TH margin 2e-3.
// ---------------------------------------------------------------------------
__global__ __launch_bounds__(256) void prepass_mfma(
    const float* __restrict__ A, const ushort* __restrict__ Wcth,
    const ushort* __restrict__ Wctl, const float* __restrict__ bc,
    int* __restrict__ rowlist, int* __restrict__ nrowsp)
{
    __shared__ union __align__(16) SM {
        struct { ushort Ah[32][40]; ushort Al[32][40];
                 ushort Bh[96][40]; ushort Bl[96][40]; } t;   // 20 KB
        float Ssc[32][97];                                    // 12.4 KB
    } sm;

    const int tid = threadIdx.x;
    const int row0 = blockIdx.x * 32;
    const int lane = tid & 63;
    const int w = tid >> 6;
    const int rowOff = (w & 1) * 16;
    const int colOff = (w >> 1) * 48;

    // A staging: 32 rows x 32 k, float4 -> 4 hi + 4 lo bf16 per thread
    const int arow = tid >> 3;         // 0..31
    const int ak4 = (tid & 7) * 4;     // 0,4..28
    // B staging: threads 0..191: col = tid>>1, k-half = (tid&1)*16
    const int bcol = tid >> 1;
    const int bkh = (tid & 1) * 16;

    f32x4 acc0 = {0.f, 0.f, 0.f, 0.f};
    f32x4 acc1 = {0.f, 0.f, 0.f, 0.f};
    f32x4 acc2 = {0.f, 0.f, 0.f, 0.f};

    // prologue prefetch (k0 = 0)
    float4 avP = *(const float4*)(A + (size_t)(row0 + arow) * FF_ + ak4);
    uint4 bhP0 = make_uint4(0,0,0,0), bhP1 = make_uint4(0,0,0,0);
    uint4 blP0 = make_uint4(0,0,0,0), blP1 = make_uint4(0,0,0,0);
    if (tid < 192) {
        const ushort* sh = Wcth + (size_t)bcol * FF_ + bkh;
        const ushort* sl = Wctl + (size_t)bcol * FF_ + bkh;
        bhP0 = *(const uint4*)(sh);  bhP1 = *(const uint4*)(sh + 8);
        blP0 = *(const uint4*)(sl);  blP1 = *(const uint4*)(sl + 8);
    }

    for (int k0 = 0; k0 < FF_; k0 += 32) {
        // stage A (split hi/lo in-register)
        {
            float vv[4] = {avP.x, avP.y, avP.z, avP.w};
            ushort hh[4], ll[4];
#pragma unroll
            for (int j = 0; j < 4; ++j) {
                hh[j] = bf16_hi(vv[j]);
                const float hf = __uint_as_float(((unsigned)hh[j]) << 16);
                ll[j] = bf16_hi(vv[j] - hf);
            }
            *(uint2*)&sm.t.Ah[arow][ak4] = make_uint2(
                (unsigned)hh[0] | ((unsigned)hh[1] << 16),
                (unsigned)hh[2] | ((unsigned)hh[3] << 16));
            *(uint2*)&sm.t.Al[arow][ak4] = make_uint2(
                (unsigned)ll[0] | ((unsigned)ll[1] << 16),
                (unsigned)ll[2] | ((unsigned)ll[3] << 16));
        }
        if (tid < 192) {
            *(uint4*)&sm.t.Bh[bcol][bkh]     = bhP0;
            *(uint4*)&sm.t.Bh[bcol][bkh + 8] = bhP1;
            *(uint4*)&sm.t.Bl[bcol][bkh]     = blP0;
            *(uint4*)&sm.t.Bl[bcol][bkh + 8] = blP1;
        }

        // prefetch next tiles
        const int kn = k0 + 32;
        if (kn < FF_) {
            avP = *(const float4*)(A + (size_t)(row0 + arow) * FF_ + kn + ak4);
            if (tid < 192) {
                const ushort* sh = Wcth + (size_t)bcol * FF_ + kn + bkh;
                const ushort* sl = Wctl + (size_t)bcol * FF_ + kn + bkh;
                bhP0 = *(const uint4*)(sh);  bhP1 = *(const uint4*)(sh + 8);
                blP0 = *(const uint4*)(sl);  blP1 = *(const uint4*)(sl + 8);
            }
        }
        __syncthreads();

        const int ar = rowOff + (lane & 15);
        const int ke = (lane >> 4) * 8;
        const bf16x8 aH = *(const bf16x8*)&sm.t.Ah[ar][ke];
        const bf16x8 aL = *(const bf16x8*)&sm.t.Al[ar][ke];
#pragma unroll
        for (int ct = 0; ct < 3; ++ct) {
            const int bc_ = colOff + ct * 16 + (lane & 15);
            const bf16x8 bH = *(const bf16x8*)&sm.t.Bh[bc_][ke];
            const bf16x8 bL = *(const bf16x8*)&sm.t.Bl[bc_][ke];
            f32x4* acc = (ct == 0) ? &acc0 : (ct == 1) ? &acc1 : &acc2;
            *acc = __builtin_amdgcn_mfma_f32_16x16x32_bf16(aH, bH, *acc, 0, 0, 0);
            *acc = __builtin_amdgcn_mfma_f32_16x16x32_bf16(aH, bL, *acc, 0, 0, 0);
            *acc = __builtin_amdgcn_mfma_f32_16x16x32_bf16(aL, bH, *acc, 0, 0, 0);
        }
        __syncthreads();
    }

    // write logits to Ssc overlay (tiles dead after final barrier)
    {
        const int r0 = rowOff + (lane >> 4) * 4;
        const int cb = colOff + (lane & 15);
#pragma unroll
        for (int reg = 0; reg < 4; ++reg) {
            const int row = r0 + reg;
            int c = cb;
            if (c < CC_) sm.Ssc[row][c] = acc0[reg] + bc[c];
            c = cb + 16;
            if (c < CC_) sm.Ssc[row][c] = acc1[reg] + bc[c];
            c = cb + 32;
            if (c < CC_) sm.Ssc[row][c] = acc2[reg] + bc[c];
        }
    }
    __syncthreads();

    // per-row filter: max fg approx score vs PRE_TH
    if (tid < 32) {
        float m_all = sm.Ssc[tid][0];
        float m_fg = -INFINITY;
        for (int c = 1; c < CC_; ++c) {
            const float lv = sm.Ssc[tid][c];
            m_all = fmaxf(m_all, lv);
            m_fg = fmaxf(m_fg, lv);
        }
        float denom = 0.f;
        for (int c = 0; c < CC_; ++c) denom += expf(sm.Ssc[tid][c] - m_all);
        const float maxsc = expf(m_fg - m_all) / denom;
        if (maxsc > PRE_TH) {
            const int pos = atomicAdd(nrowsp, 1);
            rowlist[pos] = row0 + tid;   // capacity 16000: cannot overflow
        }
    }
}

// ---------------------------------------------------------------------------
// Kernel 1b (FUSED): fp64 logits on gathered rows + fused decode.
// (byte-identical to R15/R16 — bit-exact selection math)
// ---------------------------------------------------------------------------
template<bool USE_T>
__global__ __launch_bounds__(512) void logits_fp64_rows(
    const float* __restrict__ A, const float* __restrict__ Wc,
    const float* __restrict__ bc,
    const float* __restrict__ Wb, const float* __restrict__ Wbt,
    const float* __restrict__ bb, const float* __restrict__ props,
    const int* __restrict__ rowlist, const int* __restrict__ nrowsp,
    float* __restrict__ cs, int* __restrict__ clab,
    int* __restrict__ corig, int* __restrict__ cpidx,
    int* __restrict__ cnt,
    float* __restrict__ cx1, float* __restrict__ cy1,
    float* __restrict__ cx2, float* __restrict__ cy2)
{
    const int nr = *nrowsp;
    const int row0 = blockIdx.x * 8;
    if (row0 >= nr) return;

    __shared__ union __align__(16) SM {
        struct { float Af[2][16][12]; float Bs[2][16][98]; } t;   // 14 KB
        struct { int cp[BLK_CAND]; int cc[BLK_CAND]; int cg[BLK_CAND]; } d;
    } sm;
    __shared__ __align__(16) double dcomb[256][3];  // 6 KB
    __shared__ float Ssc[8][97];                    // 3.1 KB
    __shared__ int ncand;

    const int tid = threadIdx.x;
    const int kg = tid >> 8;
    const int l = tid & 255;
    const int kbase = kg * 512;
    const int r = l >> 5;              // row 0..7
    const int c0 = (l & 31) * 3;       // col base 0..93

    if (tid == 0) ncand = 0;

    const int aslot = l >> 2;          // 0..7 (l<32)
    const int akq = (l & 3) * 4;
    const float* Arow = nullptr;
    if (l < 32) {
        const int ridx = min(row0 + aslot, nr - 1);
        Arow = A + (size_t)rowlist[ridx] * FF_ + kbase;
    }
    const int bk = l >> 4;
    const int bn = (l & 15) * 6;

    double acc[3] = {0.0, 0.0, 0.0};

    float4 avP = make_float4(0.f, 0.f, 0.f, 0.f);
    if (l < 32) avP = *reinterpret_cast<const float4*>(Arow + akq);
    float bvP[6];
#pragma unroll
    for (int jj = 0; jj < 6; ++jj) {
        const int c = bn + jj;
        bvP[jj] = (c < CC_) ? Wc[(size_t)(kbase + bk) * CC_ + c] : 0.f;
    }

    for (int k0 = 0; k0 < 512; k0 += 16) {
        if (l < 32) {
            sm.t.Af[kg][akq + 0][aslot] = avP.x;
            sm.t.Af[kg][akq + 1][aslot] = avP.y;
            sm.t.Af[kg][akq + 2][aslot] = avP.z;
            sm.t.Af[kg][akq + 3][aslot] = avP.w;
        }
#pragma unroll
        for (int jj = 0; jj < 6; ++jj) sm.t.Bs[kg][bk][bn + jj] = bvP[jj];

        const int kn = k0 + 16;
        if (kn < 512) {
            if (l < 32)
                avP = *reinterpret_cast<const float4*>(Arow + kn + akq);
#pragma unroll
            for (int jj = 0; jj < 6; ++jj) {
                const int c = bn + jj;
                bvP[jj] = (c < CC_) ? Wc[(size_t)(kbase + kn + bk) * CC_ + c] : 0.f;
            }
        }
        __syncthreads();

#pragma unroll
        for (int k = 0; k < 16; ++k) {
            const double a0 = (double)sm.t.Af[kg][k][r];
            const double b0 = (double)sm.t.Bs[kg][k][c0 + 0];
            const double b1 = (double)sm.t.Bs[kg][k][c0 + 1];
            const double b2 = (double)sm.t.Bs[kg][k][c0 + 2];
            acc[0] += a0 * b0;
            acc[1] += a0 * b1;
            acc[2] += a0 * b2;
        }
        __syncthreads();
    }

    if (kg == 1) {
#pragma unroll
        for (int j = 0; j < 3; ++j) dcomb[l][j] = acc[j];
    }
    __syncthreads();
    if (kg == 0) {
#pragma unroll
        for (int j = 0; j < 3; ++j) {
            const int c = c0 + j;
            if (c < CC_) {
                const double v = acc[j] + dcomb[l][j];
                Ssc[r][c] = __fadd_rn((float)v, bc[c]);
            }
        }
    }
    __syncthreads();

    {
        const int w = tid >> 6;
        const int lane = tid & 63;
        if (w < 8 && row0 + w < nr) {
            const int p = rowlist[row0 + w];
            const int b = p / PP_;
            const int pi = p - b * PP_;

            const float l1 = Ssc[w][lane];
            const float l2 = (lane < CC_ - 64) ? Ssc[w][lane + 64] : -INFINITY;
            float m = fmaxf(l1, l2);
#pragma unroll
            for (int off = 32; off > 0; off >>= 1)
                m = fmaxf(m, __shfl_xor(m, off));

            double d = exp((double)l1 - (double)m);
            if (lane < CC_ - 64) d += exp((double)l2 - (double)m);
#pragma unroll
            for (int off = 1; off < 64; off <<= 1)
                d += __shfl_xor(d, off);

#pragma unroll
            for (int q = 0; q < 2; ++q) {
                const int c = lane + q * 64;
                if (c >= 1 && c < CC_) {
                    const double sd = exp((double)Ssc[w][c] - (double)m) / d;
                    const float score = (float)sd;
                    if (score > SCORE_TH) {
                        const int pos = atomicAdd(&cnt[b], 1);
                        if (pos < CAP_) {
                            const int g = b * CAP_ + pos;
                            cs[g] = score;
                            clab[g] = c;
                            corig[g] = pi * (CC_ - 1) + (c - 1);
                            cpidx[g] = p;
                            const int slot = atomicAdd(&ncand, 1);
                            if (slot < BLK_CAND) {
                                sm.d.cp[slot] = p;
                                sm.d.cc[slot] = c;
                                sm.d.cg[slot] = g;
                            }
                        }
                    }
                }
            }
        }
    }
    __syncthreads();

    {
        const int w = tid >> 6;
        const int lane = tid & 63;
        const int nc = min(ncand, BLK_CAND);
        for (int ci = w; ci < nc; ci += 8) {
            const int p = sm.d.cp[ci];
            const int c = sm.d.cc[ci];
            const int g = sm.d.cg[ci];

            const float* fr = A + (size_t)p * FF_;
            double a0 = 0.0, a1 = 0.0, a2 = 0.0, a3 = 0.0;
            if (USE_T) {
                const float* w0 = Wbt + (size_t)c * 4096;
                for (int k = lane; k < FF_; k += 64) {
                    const double f = (double)fr[k];
                    a0 += f * (double)w0[k];
                    a1 += f * (double)w0[1024 + k];
                    a2 += f * (double)w0[2048 + k];
                    a3 += f * (double)w0[3072 + k];
                }
            } else {
                const float* wb0 = Wb + 4 * c;
                for (int k = lane; k < FF_; k += 64) {
                    const double f = (double)fr[k];
                    const float4 wv = *reinterpret_cast<const float4*>(
                        wb0 + (size_t)k * (CC_ * 4));
                    a0 += f * (double)wv.x; a1 += f * (double)wv.y;
                    a2 += f * (double)wv.z; a3 += f * (double)wv.w;
                }
            }
#pragma unroll
            for (int off = 32; off > 0; off >>= 1) {
                a0 += __shfl_xor(a0, off);
                a1 += __shfl_xor(a1, off);
                a2 += __shfl_xor(a2, off);
                a3 += __shfl_xor(a3, off);
            }

            if (lane == 0) {
                const float dx = __fadd_rn((float)a0, bb[4 * c + 0]);
                const float dy = __fadd_rn((float)a1, bb[4 * c + 1]);
                const float clipf = (float)BBOX_CLIP_D;
                const float dw = fminf(__fadd_rn((float)a2, bb[4 * c + 2]), clipf);
                const float dh = fminf(__fadd_rn((float)a3, bb[4 * c + 3]), clipf);

                const float px1 = props[(size_t)p * 4 + 0];
                const float py1 = props[(size_t)p * 4 + 1];
                const float px2 = props[(size_t)p * 4 + 2];
                const float py2 = props[(size_t)p * 4 + 3];
                const float wq = __fsub_rn(px2, px1);
                const float hq = __fsub_rn(py2, py1);
                const float cxq = __fadd_rn(px1, __fmul_rn(0.5f, wq));
                const float cyq = __fadd_rn(py1, __fmul_rn(0.5f, hq));

                const float pcx = __fadd_rn(__fmul_rn(dx, wq), cxq);
                const float pcy = __fadd_rn(__fmul_rn(dy, hq), cyq);
                const float ew = (float)exp((double)dw);
                const float eh = (float)exp((double)dh);
                const float pw = __fmul_rn(ew, wq);
                const float ph = __fmul_rn(eh, hq);

                const float hw = __fmul_rn(0.5f, pw);
                const float hh = __fmul_rn(0.5f, ph);
                const float bx1 = fminf(fmaxf(__fsub_rn(pcx, hw), 0.f), IMG_W);
                const float by1 = fminf(fmaxf(__fsub_rn(pcy, hh), 0.f), IMG_H);
                const float bx2 = fminf(fmaxf(__fadd_rn(pcx, hw), 0.f), IMG_W);
                const float by2 = fminf(fmaxf(__fadd_rn(pcy, hh), 0.f), IMG_H);

                cx1[g] = bx1; cy1[g] = by1; cx2[g] = bx2; cy2[g] = by2;
                if (!(__fsub_rn(bx2, bx1) >= MIN_SZ && __fsub_rn(by2, by1) >= MIN_SZ)) {
                    cs[g] = -INFINITY;
                }
            }
        }
    }
}

// ---------------------------------------------------------------------------
// Kernel 3: per-(image,class) greedy NMS — one wave per (b,c) pair.
// (unchanged — bit-exact)
// ---------------------------------------------------------------------------
__global__ __launch_bounds__(64) void nms_class(
    const float* __restrict__ c_x1, const float* __restrict__ c_y1,
    const float* __restrict__ c_x2, const float* __restrict__ c_y2,
    const float* __restrict__ c_s, const int* __restrict__ c_lab,
    const int* __restrict__ c_orig, const int* __restrict__ cnt,
    ull* __restrict__ skey, float* __restrict__ sx1v, float* __restrict__ sy1v,
    float* __restrict__ sx2v, float* __restrict__ sy2v,
    int* __restrict__ slabv, int* __restrict__ scnt)
{
    const int blk = blockIdx.x;
    const int b = blk / (CC_ - 1);
    const int c = 1 + (blk - b * (CC_ - 1));
    const int lane = threadIdx.x;

    __shared__ ull kk[CLS_CAP];
    __shared__ float x1s[CLS_CAP], y1s[CLS_CAP], x2s[CLS_CAP], y2s[CLS_CAP];

    const int n = min(cnt[b], CAP_);

    int mcnt = 0;
    for (int i0 = 0; i0 < n; i0 += 64) {
        const int i = i0 + lane;
        bool take = false;
        float s = 0.f; int so = 0; int g = 0;
        if (i < n) {
            g = b * CAP_ + i;
            if (c_lab[g] == c) {
                s = c_s[g];
                if (s > 0.f) { take = true; so = c_orig[g]; }
            }
        }
        const ull bal = __ballot(take);
        if (take) {
            const int pos = mcnt + __popcll(bal & ((1ull << lane) - 1ull));
            if (pos < CLS_CAP) {
                kk[pos] = ((ull)__float_as_uint(s) << 32) |
                          (unsigned int)(0x7FFFFFFF - so);
                x1s[pos] = c_x1[g]; y1s[pos] = c_y1[g];
                x2s[pos] = c_x2[g]; y2s[pos] = c_y2[g];
            }
        }
        mcnt += (int)__popcll(bal);
    }
    mcnt = min(mcnt, CLS_CAP);
    if (mcnt == 0) return;
    __syncthreads();

    while (true) {
        ull best = 0ull;
        for (int i = lane; i < mcnt; i += 64) best = (kk[i] > best) ? kk[i] : best;
#pragma unroll
        for (int off = 32; off > 0; off >>= 1) {
            const ull o = __shfl_xor(best, off);
            best = (o > best) ? o : best;
        }
        if (best == 0ull) break;

        int wsl = -1;
        for (int i = lane; i < mcnt; i += 64) if (kk[i] == best) wsl = i;
        const ull bal = __ballot(wsl >= 0);
        const int wlane = (int)__ffsll((long long)bal) - 1;
        wsl = __shfl(wsl, wlane);

        const float wx1 = x1s[wsl], wy1 = y1s[wsl];
        const float wx2 = x2s[wsl], wy2 = y2s[wsl];

        if (lane == 0) {
            const int sp = atomicAdd(&scnt[b], 1);
            if (sp < SURV_CAP) {
                const int sg = b * SURV_CAP + sp;
                skey[sg] = best;
                sx1v[sg] = wx1; sy1v[sg] = wy1;
                sx2v[sg] = wx2; sy2v[sg] = wy2;
                slabv[sg] = c;
            }
        }

        const float off = __fmul_rn((float)c, OFF_);
        const float ax1 = __fadd_rn(wx1, off), ay1 = __fadd_rn(wy1, off);
        const float ax2 = __fadd_rn(wx2, off), ay2 = __fadd_rn(wy2, off);
        const float a1 = __fmul_rn(__fsub_rn(ax2, ax1), __fsub_rn(ay2, ay1));
        for (int i = lane; i < mcnt; i += 64) {
            if (kk[i] == 0ull) continue;
            const float bx1 = __fadd_rn(x1s[i], off), by1 = __fadd_rn(y1s[i], off);
            const float bx2 = __fadd_rn(x2s[i], off), by2 = __fadd_rn(y2s[i], off);
            const float ix1 = fmaxf(ax1, bx1), iy1 = fmaxf(ay1, by1);
            const float ix2 = fminf(ax2, bx2), iy2 = fminf(ay2, by2);
            const float inter = __fmul_rn(fmaxf(__fsub_rn(ix2, ix1), 0.f),
                                          fmaxf(__fsub_rn(iy2, iy1), 0.f));
            const float a2 = __fmul_rn(__fsub_rn(bx2, bx1), __fsub_rn(by2, by1));
            const float den = __fadd_rn(__fsub_rn(__fadd_rn(a1, a2), inter), 1e-9f);
            const float iou = __fdiv_rn(inter, den);
            if (iou > NMS_TH) kk[i] = 0ull;
        }
        __syncthreads();
    }
}

// ---------------------------------------------------------------------------
// Kernel 4: per-image merge — bitonic sort survivors by key (desc), emit
// top-100 in order. (unchanged — bit-exact)
// ---------------------------------------------------------------------------
__global__ __launch_bounds__(256) void nms_merge(
    const ull* __restrict__ skey, const float* __restrict__ sx1v,
    const float* __restrict__ sy1v, const float* __restrict__ sx2v,
    const float* __restrict__ sy2v, const int* __restrict__ slabv,
    const int* __restrict__ scnt, float* __restrict__ out)
{
    const int b = blockIdx.x;
    const int t = threadIdx.x;

    __shared__ ull k_[SURV_CAP];
    __shared__ int id_[SURV_CAP];

    const int m = min(scnt[b], SURV_CAP);
    int N2 = 128;
    while (N2 < m) N2 <<= 1;

    for (int i = t; i < N2; i += 256) {
        k_[i] = (i < m) ? skey[b * SURV_CAP + i] : 0ull;
        id_[i] = i;
    }
    __syncthreads();

    for (int ksz = 2; ksz <= N2; ksz <<= 1) {
        for (int j = ksz >> 1; j > 0; j >>= 1) {
            for (int i = t; i < N2; i += 256) {
                const int ixj = i ^ j;
                if (ixj > i) {
                    const ull a = k_[i], cc = k_[ixj];
                    const bool desc = ((i & ksz) == 0);
                    if (desc ? (a < cc) : (a > cc)) {
                        k_[i] = cc; k_[ixj] = a;
                        const int tmp = id_[i]; id_[i] = id_[ixj]; id_[ixj] = tmp;
                    }
                }
            }
            __syncthreads();
        }
    }

    const int boxes_base = 0;
    const int scores_base = BB_ * DETS_ * 4;
    const int labels_base = BB_ * DETS_ * 5;

    for (int r = t; r < DETS_; r += 256) {
        const ull key = (r < N2) ? k_[r] : 0ull;
        float* bo = out + boxes_base + (size_t)(b * DETS_ + r) * 4;
        if (key != 0ull) {
            const int sg = b * SURV_CAP + id_[r];
            bo[0] = sx1v[sg]; bo[1] = sy1v[sg];
            bo[2] = sx2v[sg]; bo[3] = sy2v[sg];
            out[scores_base + b * DETS_ + r] = __uint_as_float((unsigned)(key >> 32));
            out[labels_base + b * DETS_ + r] = (float)slabv[sg];
        } else {
            bo[0] = 0.f; bo[1] = 0.f; bo[2] = 0.f; bo[3] = 0.f;
            out[scores_base + b * DETS_ + r] = 0.f;
            out[labels_base + b * DETS_ + r] = 0.f;
        }
    }
}

// ---------------------------------------------------------------------------
extern "C" void kernel_launch(void* const* d_in, const int* in_sizes, int n_in,
                              void* d_out, int out_size, void* d_ws, size_t ws_size,
                              hipStream_t stream)
{
    const float* feat  = (const float*)d_in[0];
    const float* Wc    = (const float*)d_in[1];
    const float* bc    = (const float*)d_in[2];
    const float* Wb    = (const float*)d_in[3];
    const float* bb    = (const float*)d_in[4];
    const float* props = (const float*)d_in[5];
    for (int i = 0; i < n_in; ++i) {
        const float* q = (const float*)d_in[i];
        switch (in_sizes[i]) {
            case 16384000: feat  = q; break;  // [16000,1024]
            case 93184:    Wc    = q; break;  // [1024,91]
            case 91:       bc    = q; break;
            case 372736:   Wb    = q; break;  // [1024,364]
            case 364:      bb    = q; break;
            case 64000:    props = q; break;  // [16,1000,4]
        }
    }
    float* out = (float*)d_out;

    char* ws = (char*)d_ws;
    int*   cnt    = (int*)ws;            // 16 ints
    int*   scnt   = (int*)(ws + 64);     // 16 ints
    int*   nrowsp = (int*)(ws + 128);    // 1 int
    float* cs    = (float*)(ws + 256);
    int*   clab  = (int*)(cs + CAND_MAX);
    int*   corig = clab + CAND_MAX;
    int*   cpidx = corig + CAND_MAX;
    float* cx1   = (float*)(cpidx + CAND_MAX);
    float* cy1   = cx1 + CAND_MAX;
    float* cx2   = cy1 + CAND_MAX;
    float* cy2   = cx2 + CAND_MAX;
    ull*   skey  = (ull*)(cy2 + CAND_MAX);
    float* sx1v  = (float*)(skey + (size_t)BB_ * SURV_CAP);
    float* sy1v  = sx1v + (size_t)BB_ * SURV_CAP;
    float* sx2v  = sy1v + (size_t)BB_ * SURV_CAP;
    float* sy2v  = sx2v + (size_t)BB_ * SURV_CAP;
    int*   slabv = (int*)(sy2v + (size_t)BB_ * SURV_CAP);
    int*   rowlist = slabv + (size_t)BB_ * SURV_CAP;   // 16000 ints (pad 16384)
    ushort* Wcth = (ushort*)(rowlist + 16384);         // 96*1024 bf16
    ushort* Wctl = Wcth + 96 * FF_;                    // 96*1024 bf16
    float* Wbt   = (float*)(Wctl + 96 * FF_);          // 91*4*1024 fp32

    const size_t need = ((char*)(Wbt + CC_ * 4 * FF_)) - ws;
    const bool useT = (ws_size >= need);

    hipMemsetAsync(ws, 0, 256, stream);   // zero cnt + scnt + nrows

    wc_bf16_split<<<(96 * FF_ + 255) / 256, 256, 0, stream>>>(Wc, Wcth, Wctl);
    if (useT)
        wb_transpose<<<(CC_ * 4 * FF_ + 255) / 256, 256, 0, stream>>>(Wb, Wbt);

    prepass_mfma<<<BB_ * PP_ / 32, 256, 0, stream>>>(feat, Wcth, Wctl, bc,
        rowlist, nrowsp);

    if (useT)
        logits_fp64_rows<true><<<BB_ * PP_ / 8, 512, 0, stream>>>(
            feat, Wc, bc, Wb, Wbt, bb, props, rowlist, nrowsp,
            cs, clab, corig, cpidx, cnt, cx1, cy1, cx2, cy2);
    else
        logits_fp64_rows<false><<<BB_ * PP_ / 8, 512, 0, stream>>>(
            feat, Wc, bc, Wb, Wbt, bb, props, rowlist, nrowsp,
            cs, clab, corig, cpidx, cnt, cx1, cy1, cx2, cy2);

    nms_class<<<BB_ * (CC_ - 1), 64, 0, stream>>>(
        cx1, cy1, cx2, cy2, cs, clab, corig, cnt,
        skey, sx1v, sy1v, sx2v, sy2v, slabv, scnt);

    nms_merge<<<BB_, 256, 0, stream>>>(
        skey, sx1v, sy1v, sx2v, sy2v, slabv, scnt, out);
}